// Round 14
// baseline (1483.803 us; speedup 1.0000x reference)
//
#include <hip/hip_runtime.h>
#include <hip/hip_bf16.h>

// Problem constants
#define BB 32
#define NT 64
#define NS 256
#define NN 320
#define NPS 256
#define DD 768
#define HH 12
#define DHD 64
#define LK 180
#define NREM 76

// ws layout (float-element offsets). Peak 32.18M f = 128.7MB.
#define OFF_HF    0LL
#define OFF_KF    7864320LL
#define OFF_QTF   15728640LL
#define OFF_QV    17301504LL
#define OFF_WQVT  25165824LL
#define OFF_HB    26000000LL
#define OFF_XA    0LL
#define OFF_X1    12000000LL
#define OFF_X2    0LL
#define OFF_SN    6000000LL
#define OFF_PSB   17301504LL
#define OFF_QT2   20500000LL
#define OFF_KT    22800000LL
#define OFF_VT    26000000LL
#define OFF_SA    6000000LL
#define OFF_H2    12000000LL
#define OFF_MIDB  15000000LL
#define OFF_WTS2  29300000LL
#define OFF_ATP   30500000LL
#define OFF_TOPK  30600000LL
#define OFF_WSM   30700000LL

// d_out (f32) offsets: (x, git, keep, removed, attn)
#define O_X    0LL
#define O_GIT  5996544LL
#define O_KEEP 5998592LL
#define O_REM  6004352LL
#define O_ATTN 6006784LL

typedef __attribute__((ext_vector_type(8))) short short8v;
typedef __attribute__((ext_vector_type(4))) float f32x4;

__device__ __forceinline__ float bf2f(unsigned short u) {
  return __uint_as_float((unsigned)u << 16);
}
__device__ __forceinline__ unsigned short f2bfu(float f) {
  __hip_bfloat16 h = __float2bfloat16(f);
  return *reinterpret_cast<unsigned short*>(&h);
}
__device__ __forceinline__ void gload16(const unsigned short* g, unsigned short* l) {
  __builtin_amdgcn_global_load_lds(
      (const __attribute__((address_space(1))) unsigned int*)g,
      (__attribute__((address_space(3))) unsigned int*)l, 16, 0, 0);
}

// ---------------- LayerNorm. OMODE: 0=f32, 1=bf16, 3=both -------------------
template<int OMODE>
__global__ __launch_bounds__(256) void ln_kernel(
    const float* __restrict__ in, float* __restrict__ outf,
    unsigned short* __restrict__ outh,
    const float* __restrict__ g, const float* __restrict__ b,
    int rpb, long long bstride, int row0)
{
  int r = blockIdx.x, t = threadIdx.x;
  long long base = (long long)(r / rpb) * bstride + (long long)(r % rpb + row0) * DD;
  float v0 = in[base + t], v1 = in[base + 256 + t], v2 = in[base + 512 + t];
  __shared__ float red[256];
  red[t] = v0 + v1 + v2;
  __syncthreads();
  #pragma unroll
  for (int off = 128; off > 0; off >>= 1) { if (t < off) red[t] += red[t + off]; __syncthreads(); }
  float mean = red[0] * (1.f / 768.f);
  __syncthreads();
  float d0 = v0 - mean, d1 = v1 - mean, d2 = v2 - mean;
  red[t] = d0 * d0 + d1 * d1 + d2 * d2;
  __syncthreads();
  #pragma unroll
  for (int off = 128; off > 0; off >>= 1) { if (t < off) red[t] += red[t + off]; __syncthreads(); }
  float rstd = rsqrtf(red[0] * (1.f / 768.f) + 1e-5f);
  long long ob = (long long)r * DD;
  float o0 = d0 * rstd * g[t]       + b[t];
  float o1 = d1 * rstd * g[256 + t] + b[256 + t];
  float o2 = d2 * rstd * g[512 + t] + b[512 + t];
  if (OMODE == 0 || OMODE == 3) {
    outf[ob + t] = o0; outf[ob + 256 + t] = o1; outf[ob + 512 + t] = o2;
  }
  if (OMODE == 1 || OMODE == 3) {
    outh[ob + t] = f2bfu(o0); outh[ob + 256 + t] = f2bfu(o1); outh[ob + 512 + t] = f2bfu(o2);
  }
}

// ------ Transpose+convert: W f32 [K][Nfull] -> bf16 [N][K]; z-planes --------
__global__ __launch_bounds__(256) void cvt_wt(
    const float* __restrict__ W, unsigned short* __restrict__ Th,
    int K, int Nfull, int n0off, int zoff, long long zdststep)
{
  __shared__ float tile[32][33];
  int z = blockIdx.z;
  unsigned short* T = Th + (long long)z * zdststep;
  int ncol = n0off + z * zoff;
  int n0 = blockIdx.x * 32, k0 = blockIdx.y * 32;
  int tx = threadIdx.x & 31, ty4 = (threadIdx.x >> 5) * 4;
  #pragma unroll
  for (int i = 0; i < 4; ++i)
    tile[ty4 + i][tx] = W[(long long)(k0 + ty4 + i) * Nfull + ncol + n0 + tx];
  __syncthreads();
  #pragma unroll
  for (int i = 0; i < 4; ++i)
    T[(long long)(n0 + ty4 + i) * K + k0 + tx] = f2bfu(tile[tx][ty4 + i]);
}

// ------ 5 small weights [768][768] -> bf16 [768][768]^T planes --------------
__global__ __launch_bounds__(256) void cvt_w5(
    const float* __restrict__ Wa, const float* __restrict__ Wb,
    const float* __restrict__ Wc, const float* __restrict__ Wd,
    const float* __restrict__ We, unsigned short* __restrict__ Th)
{
  __shared__ float tile[32][33];
  const float* srcs[5] = {Wa, Wb, Wc, Wd, We};
  const float* W = srcs[blockIdx.z];
  unsigned short* T = Th + (long long)blockIdx.z * (768 * 768);
  int n0 = blockIdx.x * 32, k0 = blockIdx.y * 32;
  int tx = threadIdx.x & 31, ty4 = (threadIdx.x >> 5) * 4;
  #pragma unroll
  for (int i = 0; i < 4; ++i)
    tile[ty4 + i][tx] = W[(long long)(k0 + ty4 + i) * 768 + n0 + tx];
  __syncthreads();
  #pragma unroll
  for (int i = 0; i < 4; ++i)
    T[(long long)(n0 + ty4 + i) * 768 + k0 + tx] = f2bfu(tile[tx][ty4 + i]);
}

// ---------------- f32 -> bf16 copy (vectorized) -----------------------------
__global__ __launch_bounds__(256) void cvt_bf_kernel(
    const float* __restrict__ in, unsigned short* __restrict__ out, long long n)
{
  long long i = ((long long)blockIdx.x * 256 + threadIdx.x) * 4;
  if (i < n) {
    float4 v = *reinterpret_cast<const float4*>(&in[i]);
    ushort4 o;
    o.x = f2bfu(v.x); o.y = f2bfu(v.y); o.z = f2bfu(v.z); o.w = f2bfu(v.w);
    *reinterpret_cast<ushort4*>(&out[i]) = o;
  }
}

// -------- f32 vector GEMM (order-critical): 512 thr, LDS double-buffer ------
__global__ __launch_bounds__(512) void gemm_k(
    const float* __restrict__ A, int a_rpb, long long a_bstride,
    const float* __restrict__ W, int wst,
    float* __restrict__ Cf, int c_ld, int M, int K)
{
  __shared__ float As[2][16][132];
  __shared__ float Ws[2][16][132];
  int t = threadIdx.x;
  long long bm = (long long)blockIdx.y * 128;
  long long bn = (long long)blockIdx.x * 128;
  float acc[4][8] = {};
  int wid = t >> 6, lane = t & 63;
  int tm = (wid & 3) * 32 + (lane >> 3) * 4;
  int tn = (wid >> 2) * 64 + (lane & 7) * 8;
  int idx = t << 2;
  int am = idx >> 4, ak = idx & 15;
  int wk = idx >> 7, wn2 = idx & 127;
  long long r = bm + am;
  long long abase = (r / a_rpb) * a_bstride + (r % a_rpb) * (long long)K;
  float4 a4 = *reinterpret_cast<const float4*>(A + abase + ak);
  float4 w4 = *reinterpret_cast<const float4*>(W + (long long)wk * wst + bn + wn2);
  As[0][ak + 0][am] = a4.x; As[0][ak + 1][am] = a4.y;
  As[0][ak + 2][am] = a4.z; As[0][ak + 3][am] = a4.w;
  *reinterpret_cast<float4*>(&Ws[0][wk][wn2]) = w4;
  __syncthreads();
  int cur = 0;
  for (int k0 = 0; k0 < K; k0 += 16) {
    bool more = (k0 + 16 < K);
    if (more) {
      a4 = *reinterpret_cast<const float4*>(A + abase + k0 + 16 + ak);
      w4 = *reinterpret_cast<const float4*>(W + (long long)(k0 + 16 + wk) * wst + bn + wn2);
    }
    #pragma unroll
    for (int kk = 0; kk < 16; ++kk) {
      float a[4], w[8];
      *reinterpret_cast<float4*>(a)     = *reinterpret_cast<const float4*>(&As[cur][kk][tm]);
      *reinterpret_cast<float4*>(w)     = *reinterpret_cast<const float4*>(&Ws[cur][kk][tn]);
      *reinterpret_cast<float4*>(w + 4) = *reinterpret_cast<const float4*>(&Ws[cur][kk][tn + 4]);
      #pragma unroll
      for (int i = 0; i < 4; ++i)
        #pragma unroll
        for (int j = 0; j < 8; ++j)
          acc[i][j] = fmaf(a[i], w[j], acc[i][j]);
    }
    if (more) {
      As[cur ^ 1][ak + 0][am] = a4.x; As[cur ^ 1][ak + 1][am] = a4.y;
      As[cur ^ 1][ak + 2][am] = a4.z; As[cur ^ 1][ak + 3][am] = a4.w;
      *reinterpret_cast<float4*>(&Ws[cur ^ 1][wk][wn2]) = w4;
    }
    __syncthreads();
    cur ^= 1;
  }
  #pragma unroll
  for (int i = 0; i < 4; ++i) {
    long long crow = (bm + tm + i) * c_ld;
    #pragma unroll
    for (int j = 0; j < 8; ++j)
      Cf[crow + bn + tn + j] = acc[i][j];
  }
}

// -------- MFMA GEMM v2 (m97 pattern): global_load_lds + linear LDS ----------
__global__ __launch_bounds__(256) void gemm_mfma(
    const unsigned short* __restrict__ A, const unsigned short* __restrict__ Bt,
    const float* __restrict__ bias, const float* __restrict__ resid,
    float* __restrict__ Cf, int ldf,
    unsigned short* __restrict__ Cb, int ldb, int colsplit,
    int M, int N, int K,
    int c_rpb, long long c_bstride, int c_row0, int act)
{
  __shared__ unsigned short As[128 * 32], Bs[128 * 32];
  int t = threadIdx.x;
  long long bm = (long long)blockIdx.y * 128;
  long long bn = (long long)blockIdx.x * 128;
  int wid = t >> 6, lane = t & 63;
  int wr = (wid >> 1) << 6, wc = (wid & 1) << 6;
  int e0 = (wid << 9) + lane * 8;
  int e1 = ((4 + wid) << 9) + lane * 8;
  int r0 = e0 >> 5, c0 = e0 & 31;
  int r1 = e1 >> 5, c1 = e1 & 31;
  unsigned short* As0 = &As[(long long)(wid << 9)];
  unsigned short* As1 = &As[(long long)((4 + wid) << 9)];
  unsigned short* Bs0 = &Bs[(long long)(wid << 9)];
  unsigned short* Bs1 = &Bs[(long long)((4 + wid) << 9)];
  const unsigned short* Ar0 = A + (bm + r0) * (long long)K + c0;
  const unsigned short* Ar1 = A + (bm + r1) * (long long)K + c1;
  const unsigned short* Br0 = Bt + (bn + r0) * (long long)K + c0;
  const unsigned short* Br1 = Bt + (bn + r1) * (long long)K + c1;
  f32x4 acc[4][4];
  #pragma unroll
  for (int m = 0; m < 4; ++m)
    #pragma unroll
    for (int n = 0; n < 4; ++n) acc[m][n] = (f32x4){0.f, 0.f, 0.f, 0.f};
  int ra = (wr + (lane & 15)) * 32 + ((lane >> 4) << 3);
  int rb = (wc + (lane & 15)) * 32 + ((lane >> 4) << 3);
  for (int k0 = 0; k0 < K; k0 += 32) {
    gload16(Ar0 + k0, As0);
    gload16(Ar1 + k0, As1);
    gload16(Br0 + k0, Bs0);
    gload16(Br1 + k0, Bs1);
    __syncthreads();
    short8v a[4], b[4];
    #pragma unroll
    for (int m = 0; m < 4; ++m) {
      a[m] = *reinterpret_cast<const short8v*>(&As[ra + m * 512]);
      b[m] = *reinterpret_cast<const short8v*>(&Bs[rb + m * 512]);
    }
    #pragma unroll
    for (int m = 0; m < 4; ++m)
      #pragma unroll
      for (int n = 0; n < 4; ++n)
        acc[m][n] = __builtin_amdgcn_mfma_f32_16x16x32_bf16(a[m], b[n], acc[m][n], 0, 0, 0);
    __syncthreads();
  }
  int ro = (lane >> 4) << 2, co = lane & 15;
  #pragma unroll
  for (int m = 0; m < 4; ++m) {
    #pragma unroll
    for (int j = 0; j < 4; ++j) {
      long long r = bm + wr + m * 16 + ro + j;
      long long base = (r / c_rpb) * c_bstride + (long long)((int)(r % c_rpb) + c_row0) * ldf;
      #pragma unroll
      for (int n = 0; n < 4; ++n) {
        long long c = bn + wc + n * 16 + co;
        float v = acc[m][n][j];
        if (bias) v += bias[c];
        if (act) v = 0.5f * v * (1.f + erff(v * 0.70710678118654752f));
        if (resid) v += resid[base + c];
        if (c < colsplit) Cf[base + c] = v;
        else Cb[r * ldb + (c - colsplit)] = f2bfu(v);
      }
    }
  }
}

// ======== MFMA flash attention (value path) — round-8 exact =================
template<int NKV, int NW, int PROBS, int KF32>
__global__ __launch_bounds__(NW * 64) void attn_mfma(
    const unsigned short* __restrict__ q, int q_rs, int q_bs, int q_off,
    const void* __restrict__ kv, int k_rs,
    const unsigned short* __restrict__ v, int v_rs,
    unsigned short* __restrict__ xab, int xa_rs, int xa_bs, int xa_off,
    float* __restrict__ probs, int NQtot)
{
  constexpr int KST = 68;
  constexpr int VST = NKV + 4;
  constexpr int NT_K = NKV / 16;
  constexpr int NTH = NW * 64;
  __shared__ unsigned short ksh[NKV * KST];
  __shared__ unsigned short qsh[NW * 16 * KST];
  __shared__ unsigned short vsh[64 * VST];
  __shared__ float ldsT[PROBS ? NW * 16 * 17 : 1];
  int bh = blockIdx.x, b = bh / HH, h = bh % HH;
  int rb = blockIdx.y * (NW * 16);
  int t = threadIdx.x;
  const float* kf = (const float*)kv;
  const unsigned short* ku = (const unsigned short*)kv;
  for (int i = t; i < NKV * 64; i += NTH) {
    int kr = i >> 6, d = i & 63;
    long long gi = (long long)(b * NKV + kr);
    ksh[kr * KST + d] = KF32 ? f2bfu(kf[gi * k_rs + h * DHD + d])
                             : ku[gi * k_rs + h * DHD + d];
    int kp = (kr & ~31) | (((kr >> 2) & 3) << 3) | (((kr >> 4) & 1) << 2) | (kr & 3);
    vsh[d * VST + kp] = v[gi * v_rs + h * DHD + d];
  }
  for (int i = t; i < NW * 16 * 64; i += NTH) {
    int qr = i >> 6, d = i & 63;
    int qg = rb + qr;
    qsh[qr * KST + d] = (qg < NQtot)
      ? q[(long long)(b * q_bs + q_off + qg) * q_rs + h * DHD + d] : (unsigned short)0;
  }
  __syncthreads();
  int wid = t >> 6, lane = t & 63;
  int l15 = lane & 15, lg = lane >> 4;
  short8v bq[2];
  #pragma unroll
  for (int ks = 0; ks < 2; ++ks)
    bq[ks] = *reinterpret_cast<const short8v*>(&qsh[(wid * 16 + l15) * KST + ks * 32 + lg * 8]);
  f32x4 s[NT_K];
  #pragma unroll
  for (int mt = 0; mt < NT_K; ++mt) s[mt] = (f32x4){0.f, 0.f, 0.f, 0.f};
  #pragma unroll
  for (int mt = 0; mt < NT_K; ++mt)
    #pragma unroll
    for (int ks = 0; ks < 2; ++ks) {
      short8v ka = *reinterpret_cast<const short8v*>(&ksh[(mt * 16 + l15) * KST + ks * 32 + lg * 8]);
      s[mt] = __builtin_amdgcn_mfma_f32_16x16x32_bf16(ka, bq[ks], s[mt], 0, 0, 0);
    }
  float m = -3.4e38f;
  #pragma unroll
  for (int mt = 0; mt < NT_K; ++mt)
    #pragma unroll
    for (int j = 0; j < 4; ++j) { s[mt][j] *= 0.125f; m = fmaxf(m, s[mt][j]); }
  m = fmaxf(m, __shfl_xor(m, 16)); m = fmaxf(m, __shfl_xor(m, 32));
  float ss = 0.f;
  #pragma unroll
  for (int mt = 0; mt < NT_K; ++mt)
    #pragma unroll
    for (int j = 0; j < 4; ++j) { s[mt][j] = __expf(s[mt][j] - m); ss += s[mt][j]; }
  ss += __shfl_xor(ss, 16); ss += __shfl_xor(ss, 32);
  float inv = 1.f / ss;
  #pragma unroll
  for (int mt = 0; mt < NT_K; ++mt)
    #pragma unroll
    for (int j = 0; j < 4; ++j) s[mt][j] *= inv;
  if (PROBS) {
    float* lT = &ldsT[wid * 16 * 17];
    #pragma unroll
    for (int mt = 0; mt < NT_K; ++mt) {
      #pragma unroll
      for (int j = 0; j < 4; ++j) lT[l15 * 17 + lg * 4 + j] = s[mt][j];
      #pragma unroll
      for (int m4 = 0; m4 < 4; ++m4) {
        int qg = rb + wid * 16 + m4 * 4 + lg;
        if (qg < NQtot)
          probs[((long long)(bh * q_bs + q_off + qg)) * NKV + mt * 16 + l15] =
              lT[(m4 * 4 + lg) * 17 + l15];
      }
    }
  }
  f32x4 o[4];
  #pragma unroll
  for (int nt = 0; nt < 4; ++nt) o[nt] = (f32x4){0.f, 0.f, 0.f, 0.f};
  #pragma unroll
  for (int c = 0; c < NKV / 32; ++c) {
    short8v a8;
    #pragma unroll
    for (int j = 0; j < 4; ++j) {
      a8[j]     = (short)f2bfu(s[2 * c][j]);
      a8[4 + j] = (short)f2bfu(s[2 * c + 1][j]);
    }
    #pragma unroll
    for (int nt = 0; nt < 4; ++nt) {
      short8v bv = *reinterpret_cast<const short8v*>(&vsh[(nt * 16 + l15) * VST + c * 32 + lg * 8]);
      o[nt] = __builtin_amdgcn_mfma_f32_16x16x32_bf16(a8, bv, o[nt], 0, 0, 0);
    }
  }
  #pragma unroll
  for (int nt = 0; nt < 4; ++nt)
    #pragma unroll
    for (int j = 0; j < 4; ++j) {
      int qg = rb + wid * 16 + lg * 4 + j;
      if (qg < NQtot)
        xab[(long long)(b * xa_bs + xa_off + qg) * xa_rs + h * DHD + nt * 16 + l15] =
            f2bfu(o[nt][j]);
    }
}

// ---- f32 attention template rows: v3 + VGPR headroom (launch_bounds(.,4)) --
#define SOFTMAX_PV(SARR, QIDX)                                                \
  {                                                                           \
    float m = -3.4e38f;                                                       \
    _Pragma("unroll")                                                         \
    for (int r = 0; r < 5; ++r) { SARR[r] *= 0.125f; m = fmaxf(m, SARR[r]); } \
    _Pragma("unroll")                                                         \
    for (int off = 32; off > 0; off >>= 1) m = fmaxf(m, __shfl_xor(m, off));  \
    float ssum = 0.f;                                                         \
    _Pragma("unroll")                                                         \
    for (int r = 0; r < 5; ++r) { SARR[r] = __expf(SARR[r] - m); ssum += SARR[r]; } \
    _Pragma("unroll")                                                         \
    for (int off = 32; off > 0; off >>= 1) ssum += __shfl_xor(ssum, off);     \
    float inv = 1.f / ssum;                                                   \
    long long pb = ((long long)(bh * NN) + (QIDX)) * NN;                      \
    _Pragma("unroll")                                                         \
    for (int r = 0; r < 5; ++r) {                                             \
      float p = SARR[r] * inv;                                                \
      SARR[r] = p;                                                            \
      pss[wid][lane + (r << 6)] = p;                                          \
      probs[pb + lane + (r << 6)] = p;                                        \
    }                                                                         \
    _Pragma("unroll")                                                         \
    for (int r = 1; r < 5; ++r) at[r - 1] += SARR[r];                         \
    float acc = 0.f;                                                          \
    const int cv = ((lane >> 4) & 3) << 2;                                    \
    _Pragma("unroll 8")                                                       \
    for (int j = 0; j < NN; j += 4) {                                         \
      float4 p4 = *reinterpret_cast<const float4*>(&pss[wid][j]);             \
      ushort4 v4 = *reinterpret_cast<const ushort4*>(&vsh[lane * VST + (j ^ cv)]); \
      acc = fmaf(p4.x, bf2f(v4.x), acc);                                      \
      acc = fmaf(p4.y, bf2f(v4.y), acc);                                      \
      acc = fmaf(p4.z, bf2f(v4.z), acc);                                      \
      acc = fmaf(p4.w, bf2f(v4.w), acc);                                      \
    }                                                                         \
    xab[(long long)(b * NN + (QIDX)) * 768 + h * DHD + lane] = f2bfu(acc);    \
  }

// LDS (154.6KB) limits to 1 block/CU = 16 waves = 4 waves/EU; declare it so
// the compiler allocates up to 128 VGPRs instead of spilling at the 64 cap.
__global__ __launch_bounds__(1024, 4) void attn_tmpl(
    const float* __restrict__ qt, const float* __restrict__ kf,
    const unsigned short* __restrict__ vb,
    unsigned short* __restrict__ xab, float* __restrict__ probs,
    float* __restrict__ atp)
{
  constexpr int KST2 = 66;
  constexpr int VST = NN + 4;
  __shared__ float ksh[NN * KST2];
  __shared__ unsigned short vsh[64 * VST];
  __shared__ float pss[16][NN];
  __shared__ float qsh[16][2][64];
  int bh = blockIdx.x, b = bh / HH, h = bh % HH;
  int t = threadIdx.x;
  for (int i = t; i < NN * 64; i += 1024) {
    int rr = i >> 6, d = i & 63;
    long long gi = (long long)(b * NN + rr);
    ksh[rr * KST2 + (d ^ (((rr >> 4) & 3) << 1))] = kf[gi * 768 + h * DHD + d];
    vsh[d * VST + (rr ^ (((d >> 4) & 3) << 2))] = vb[gi * 1536 + h * DHD + d];
  }
  __syncthreads();
  int wid = t >> 6, lane = t & 63;
  float at[4] = {};
  #pragma unroll
  for (int qp = 0; qp < 2; ++qp) {
    int qa = wid + qp * 32, qb2 = qa + 16;
    qsh[wid][0][lane] = qt[(long long)(b * NT + qa)  * 768 + h * DHD + lane];
    qsh[wid][1][lane] = qt[(long long)(b * NT + qb2) * 768 + h * DHD + lane];
    float s0[5], s1[5];
    #pragma unroll
    for (int rr2 = 0; rr2 < 5; ++rr2) { s0[rr2] = 0.f; s1[rr2] = 0.f; }
    #pragma unroll
    for (int d = 0; d < 64; d += 2) {
      float qa0 = qsh[wid][0][d], qa1 = qsh[wid][0][d + 1];
      float qb0 = qsh[wid][1][d], qb1 = qsh[wid][1][d + 1];
      #pragma unroll
      for (int rr2 = 0; rr2 < 5; ++rr2) {
        int kr = lane + (rr2 << 6);
        float2 k2 = *reinterpret_cast<const float2*>(
            &ksh[kr * KST2 + (d ^ (((kr >> 4) & 3) << 1))]);
        s0[rr2] = fmaf(qa0, k2.x, s0[rr2]);
        s0[rr2] = fmaf(qa1, k2.y, s0[rr2]);
        s1[rr2] = fmaf(qb0, k2.x, s1[rr2]);
        s1[rr2] = fmaf(qb1, k2.y, s1[rr2]);
      }
    }
    SOFTMAX_PV(s0, qa)    // q ascending within pair: qa then qb2
    SOFTMAX_PV(s1, qb2)
  }
  #pragma unroll
  for (int r = 1; r < 5; ++r) pss[wid][lane + ((r - 1) << 6)] = at[r - 1];
  __syncthreads();
  if (t < 256) {
    float v = 0.f;
    #pragma unroll
    for (int w = 0; w < 16; ++w) v += pss[w][t];
    atp[(long long)bh * 256 + t] = v;
  }
}

// ---- Per-batch argsort(-attn_t), stable; emit keep/removed -----------------
__global__ __launch_bounds__(256) void sort_kernel(
    const float* __restrict__ atp, const int* __restrict__ gis,
    float* __restrict__ keep_out, float* __restrict__ rem_out,
    int* __restrict__ topk)
{
  int b = blockIdx.x, t = threadIdx.x;
  __shared__ float sv[256];
  __shared__ int   si[256];
  float v = 0.f;
  for (int h = 0; h < HH; ++h) v += atp[((long long)(b * HH + h) << 8) + t];
  sv[t] = v; si[t] = t;
  __syncthreads();
  for (int k = 2; k <= 256; k <<= 1) {
    for (int j = k >> 1; j > 0; j >>= 1) {
      int ixj = t ^ j;
      if (ixj > t) {
        float va = sv[t], vb2 = sv[ixj];
        int ia = si[t], ib = si[ixj];
        bool after = (va < vb2) || (va == vb2 && ia > ib);
        bool dirUp = ((t & k) == 0);
        if (after == dirUp) { sv[t] = vb2; sv[ixj] = va; si[t] = ib; si[ixj] = ia; }
      }
      __syncthreads();
    }
  }
  int o = si[t];
  if (t < LK) {
    topk[b * LK + t] = o;
    keep_out[b * LK + t] = (float)gis[(b << 8) + o];
  } else {
    rem_out[b * NREM + (t - LK)] = (float)gis[(b << 8) + o];
  }
}

__global__ __launch_bounds__(256) void gather_kernel(
    const float* __restrict__ x1, const int* __restrict__ topk, float* __restrict__ x2)
{
  int r = blockIdx.x, t = threadIdx.x;
  int b = r / 244, rr = r % 244;
  int src = (rr < NT) ? rr : (NT + topk[b * LK + (rr - NT)]);
  const float* s = x1 + (long long)(b * NN + src) * DD;
  float* d = x2 + (long long)r * DD;
  d[t] = s[t]; d[256 + t] = s[256 + t]; d[512 + t] = s[512 + t];
}

__global__ void git_kernel(const int* __restrict__ git, float* __restrict__ o)
{
  int i = blockIdx.x * 256 + threadIdx.x;
  if (i < BB * NT) o[i] = (float)git[i];
}

extern "C" void kernel_launch(void* const* d_in, const int* in_sizes, int n_in,
                              void* d_out, int out_size, void* d_ws, size_t ws_size,
                              hipStream_t stream) {
  (void)in_sizes; (void)n_in; (void)out_size; (void)ws_size;
  const float* x    = (const float*)d_in[0];
  const float* ps   = (const float*)d_in[1];
  const int*   git  = (const int*)d_in[2];
  const int*   gis  = (const int*)d_in[3];
  const float* g1   = (const float*)d_in[4];
  const float* b1   = (const float*)d_in[5];
  const float* Wqkv = (const float*)d_in[6];
  const float* Wproj= (const float*)d_in[7];
  const float* bproj= (const float*)d_in[8];
  const float* gt   = (const float*)d_in[9];
  const float* bt   = (const float*)d_in[10];
  const float* Wq   = (const float*)d_in[11];
  const float* Wk   = (const float*)d_in[12];
  const float* Wv   = (const float*)d_in[13];
  const float* Wtp  = (const float*)d_in[14];
  const float* btp  = (const float*)d_in[15];
  const float* g2   = (const float*)d_in[16];
  const float* b2   = (const float*)d_in[17];
  const float* W1   = (const float*)d_in[18];
  const float* b1m  = (const float*)d_in[19];
  const float* W2   = (const float*)d_in[20];
  const float* b2m  = (const float*)d_in[21];
  float* wsf = (float*)d_ws;
  float* out = (float*)d_out;
  unsigned short* WQVT = (unsigned short*)(wsf + OFF_WQVT);
  unsigned short* HBp  = (unsigned short*)(wsf + OFF_HB);
  unsigned short* QVp  = (unsigned short*)(wsf + OFF_QV);
  unsigned short* XAp  = (unsigned short*)(wsf + OFF_XA);
  unsigned short* WSMp = (unsigned short*)(wsf + OFF_WSM);
  unsigned short* WTS2 = (unsigned short*)(wsf + OFF_WTS2);
  unsigned short* SNp  = (unsigned short*)(wsf + OFF_SN);
  unsigned short* PSBp = (unsigned short*)(wsf + OFF_PSB);
  unsigned short* QT2p = (unsigned short*)(wsf + OFF_QT2);
  unsigned short* KTp  = (unsigned short*)(wsf + OFF_KT);
  unsigned short* VTp  = (unsigned short*)(wsf + OFF_VT);
  unsigned short* SAp  = (unsigned short*)(wsf + OFF_SA);
  unsigned short* H2p  = (unsigned short*)(wsf + OFF_H2);
  unsigned short* MIDp = (unsigned short*)(wsf + OFF_MIDB);
  #define WSLOT(i) (WSMp + (long long)(i) * 768 * 768)

  // S0a: Wqkv q-part and v-part -> 2 transposed bf16 planes
  hipLaunchKernelGGL(cvt_wt, dim3(24, 24, 2), dim3(256), 0, stream,
                     Wqkv, WQVT, DD, 3 * DD, 0, 1536, (long long)768 * 768);
  // S0b: 5 small weights -> transposed planes
  hipLaunchKernelGGL(cvt_w5, dim3(24, 24, 5), dim3(256), 0, stream,
                     Wproj, Wq, Wk, Wv, Wtp, WSMp);
  // S1: h = LN(x) -> f32 HF + bf16 HB
  hipLaunchKernelGGL((ln_kernel<3>), dim3(BB * NN), dim3(256), 0, stream,
                     x, wsf + OFF_HF, HBp, g1, b1, BB * NN, 0LL, 0);
  // S2a: k = h @ Wqkv[:,768:1536]  (f32, exact)
  hipLaunchKernelGGL(gemm_k, dim3(6, 80), dim3(512), 0, stream,
                     wsf + OFF_HF, BB * NN, 0LL, Wqkv + 768, 3 * DD,
                     wsf + OFF_KF, DD, BB * NN, DD);
  // S2b: q_template = h[template rows] @ Wqkv[:,0:768]
  hipLaunchKernelGGL(gemm_k, dim3(6, 16), dim3(512), 0, stream,
                     wsf + OFF_HF, NT, (long long)NN * DD, Wqkv, 3 * DD,
                     wsf + OFF_QTF, DD, BB * NT, DD);
  // S2c: [q|v] = h(bf16) @ [Wq-part|Wv-part]  (MFMA v2)
  hipLaunchKernelGGL(gemm_mfma, dim3(12, 80), dim3(256), 0, stream,
                     HBp, WQVT, (const float*)nullptr, (const float*)nullptr,
                     (float*)nullptr, 1, QVp, 1536, 0,
                     BB * NN, 1536, DD, BB * NN, 0LL, 0, 0);
  // S3B: MFMA attention rows 64..319 -> probs, xa
  hipLaunchKernelGGL((attn_mfma<NN, 8, 1, 1>), dim3(BB * HH, 2), dim3(512), 0, stream,
                     QVp, 1536, NN, NT,
                     (const void*)(wsf + OFF_KF), DD,
                     QVp + 768, 1536,
                     XAp, DD, NN, NT,
                     out + O_ATTN, 256);
  // S3A: f32 attention rows <64 -> probs, xa, attn_t
  hipLaunchKernelGGL(attn_tmpl, dim3(BB * HH), dim3(1024), 0, stream,
                     wsf + OFF_QTF, wsf + OFF_KF, QVp + 768,
                     XAp, out + O_ATTN, wsf + OFF_ATP);
  // S4: x1 = x + xa @ Wproj + bproj
  hipLaunchKernelGGL(gemm_mfma, dim3(6, 80), dim3(256), 0, stream,
                     XAp, WSLOT(0), bproj, x,
                     wsf + OFF_X1, DD, (unsigned short*)nullptr, 1, DD,
                     BB * NN, DD, DD, BB * NN, 0LL, 0, 0);
  // S5/S6/S7
  hipLaunchKernelGGL(sort_kernel, dim3(BB), dim3(256), 0, stream,
                     wsf + OFF_ATP, gis, out + O_KEEP, out + O_REM,
                     (int*)(wsf + OFF_TOPK));
  hipLaunchKernelGGL(git_kernel, dim3((BB * NT + 255) / 256), dim3(256), 0, stream,
                     git, out + O_GIT);
  hipLaunchKernelGGL(gather_kernel, dim3(BB * 244), dim3(256), 0, stream,
                     wsf + OFF_X1, (const int*)(wsf + OFF_TOPK), wsf + OFF_X2);
  // S7.5: ps -> bf16 (QV region dead)
  hipLaunchKernelGGL(cvt_bf_kernel, dim3(6144), dim3(256), 0, stream,
                     ps, PSBp, (long long)BB * NPS * DD);
  // S8: sn = LN(s) -> bf16
  hipLaunchKernelGGL((ln_kernel<1>), dim3(BB * LK), dim3(256), 0, stream,
                     wsf + OFF_X2, (float*)nullptr, SNp, gt, bt, LK, (long long)244 * DD, NT);
  // S9: qT = sn @ Wq -> bf16
  hipLaunchKernelGGL(gemm_mfma, dim3(6, 45), dim3(256), 0, stream,
                     SNp, WSLOT(1), (const float*)nullptr, (const float*)nullptr,
                     (float*)nullptr, 1, QT2p, DD, 0,
                     BB * LK, DD, DD, BB * LK, 0LL, 0, 0);
  // S10: kT = ps @ Wk -> bf16
  hipLaunchKernelGGL(gemm_mfma, dim3(6, 64), dim3(256), 0, stream,
                     PSBp, WSLOT(2), (const float*)nullptr, (const float*)nullptr,
                     (float*)nullptr, 1, KTp, DD, 0,
                     BB * NPS, DD, DD, BB * NPS, 0LL, 0, 0);
  // S11: vT = ps @ Wv -> bf16
  hipLaunchKernelGGL(gemm_mfma, dim3(6, 64), dim3(256), 0, stream,
                     PSBp, WSLOT(3), (const float*)nullptr, (const float*)nullptr,
                     (float*)nullptr, 1, VTp, DD, 0,
                     BB * NPS, DD, DD, BB * NPS, 0LL, 0, 0);
  // S12: stage-2 attention (MFMA) -> sa bf16
  hipLaunchKernelGGL((attn_mfma<NPS, 8, 0, 0>), dim3(BB * HH, 2), dim3(512), 0, stream,
                     QT2p, DD, LK, 0,
                     (const void*)KTp, DD,
                     VTp, DD,
                     SAp, DD, LK, 0,
                     (float*)nullptr, LK);
  // S13: s2 = s + sa @ Wtp + btp (into x2 rows 64..243)
  hipLaunchKernelGGL(gemm_mfma, dim3(6, 45), dim3(256), 0, stream,
                     SAp, WSLOT(4), btp, wsf + OFF_X2,
                     wsf + OFF_X2, DD, (unsigned short*)nullptr, 1, DD,
                     BB * LK, DD, DD, LK, (long long)244 * DD, NT, 0);
  // S14: h2 = LN(x2) -> bf16
  hipLaunchKernelGGL((ln_kernel<1>), dim3(BB * 244), dim3(256), 0, stream,
                     wsf + OFF_X2, (float*)nullptr, H2p, g2, b2, BB * 244, 0LL, 0);
  // S15: mid = gelu(h2 @ W1 + b1m) -> bf16
  hipLaunchKernelGGL(cvt_wt, dim3(96, 24, 1), dim3(256), 0, stream,
                     W1, WTS2, DD, 4 * DD, 0, 0, 0LL);
  hipLaunchKernelGGL(gemm_mfma, dim3(24, 61), dim3(256), 0, stream,
                     H2p, WTS2, b1m, (const float*)nullptr,
                     (float*)nullptr, 1, MIDp, 4 * DD, 0,
                     BB * 244, 4 * DD, DD, BB * 244, 0LL, 0, 1);
  // S16: x_out = x2 + mid @ W2 + b2m -> f32 d_out
  hipLaunchKernelGGL(cvt_wt, dim3(24, 96, 1), dim3(256), 0, stream,
                     W2, WTS2, 4 * DD, DD, 0, 0, 0LL);
  hipLaunchKernelGGL(gemm_mfma, dim3(6, 61), dim3(256), 0, stream,
                     MIDp, WTS2, b2m, wsf + OFF_X2,
                     out + O_X, DD, (unsigned short*)nullptr, 1, DD,
                     BB * 244, DD, 4 * DD, BB * 244, 0LL, 0, 0);
}

// Round 15
// 1040.897 us; speedup vs baseline: 1.4255x; 1.4255x over previous
//
#include <hip/hip_runtime.h>
#include <hip/hip_bf16.h>

// Problem constants
#define BB 32
#define NT 64
#define NS 256
#define NN 320
#define NPS 256
#define DD 768
#define HH 12
#define DHD 64
#define LK 180
#define NREM 76

// ws layout (float-element offsets). Peak 32.18M f = 128.7MB.
#define OFF_HF    0LL
#define OFF_KF    7864320LL
#define OFF_QTF   15728640LL
#define OFF_QV    17301504LL
#define OFF_WQVT  25165824LL
#define OFF_HB    26000000LL
#define OFF_XA    0LL
#define OFF_X1    12000000LL
#define OFF_X2    0LL
#define OFF_SN    6000000LL
#define OFF_PSB   17301504LL
#define OFF_QT2   20500000LL
#define OFF_KT    22800000LL
#define OFF_VT    26000000LL
#define OFF_SA    6000000LL
#define OFF_H2    12000000LL
#define OFF_MIDB  15000000LL
#define OFF_WTS2  29300000LL
#define OFF_ATP   30500000LL
#define OFF_TOPK  30600000LL
#define OFF_WSM   30700000LL

// d_out (f32) offsets: (x, git, keep, removed, attn)
#define O_X    0LL
#define O_GIT  5996544LL
#define O_KEEP 5998592LL
#define O_REM  6004352LL
#define O_ATTN 6006784LL

typedef __attribute__((ext_vector_type(8))) short short8v;
typedef __attribute__((ext_vector_type(4))) float f32x4;

__device__ __forceinline__ float bf2f(unsigned short u) {
  return __uint_as_float((unsigned)u << 16);
}
__device__ __forceinline__ unsigned short f2bfu(float f) {
  __hip_bfloat16 h = __float2bfloat16(f);
  return *reinterpret_cast<unsigned short*>(&h);
}
__device__ __forceinline__ void gload16(const unsigned short* g, unsigned short* l) {
  __builtin_amdgcn_global_load_lds(
      (const __attribute__((address_space(1))) unsigned int*)g,
      (__attribute__((address_space(3))) unsigned int*)l, 16, 0, 0);
}

// ---------------- LayerNorm. OMODE: 0=f32, 1=bf16, 3=both -------------------
template<int OMODE>
__global__ __launch_bounds__(256) void ln_kernel(
    const float* __restrict__ in, float* __restrict__ outf,
    unsigned short* __restrict__ outh,
    const float* __restrict__ g, const float* __restrict__ b,
    int rpb, long long bstride, int row0)
{
  int r = blockIdx.x, t = threadIdx.x;
  long long base = (long long)(r / rpb) * bstride + (long long)(r % rpb + row0) * DD;
  float v0 = in[base + t], v1 = in[base + 256 + t], v2 = in[base + 512 + t];
  __shared__ float red[256];
  red[t] = v0 + v1 + v2;
  __syncthreads();
  #pragma unroll
  for (int off = 128; off > 0; off >>= 1) { if (t < off) red[t] += red[t + off]; __syncthreads(); }
  float mean = red[0] * (1.f / 768.f);
  __syncthreads();
  float d0 = v0 - mean, d1 = v1 - mean, d2 = v2 - mean;
  red[t] = d0 * d0 + d1 * d1 + d2 * d2;
  __syncthreads();
  #pragma unroll
  for (int off = 128; off > 0; off >>= 1) { if (t < off) red[t] += red[t + off]; __syncthreads(); }
  float rstd = rsqrtf(red[0] * (1.f / 768.f) + 1e-5f);
  long long ob = (long long)r * DD;
  float o0 = d0 * rstd * g[t]       + b[t];
  float o1 = d1 * rstd * g[256 + t] + b[256 + t];
  float o2 = d2 * rstd * g[512 + t] + b[512 + t];
  if (OMODE == 0 || OMODE == 3) {
    outf[ob + t] = o0; outf[ob + 256 + t] = o1; outf[ob + 512 + t] = o2;
  }
  if (OMODE == 1 || OMODE == 3) {
    outh[ob + t] = f2bfu(o0); outh[ob + 256 + t] = f2bfu(o1); outh[ob + 512 + t] = f2bfu(o2);
  }
}

// ------ Transpose+convert: W f32 [K][Nfull] -> bf16 [N][K]; z-planes --------
__global__ __launch_bounds__(256) void cvt_wt(
    const float* __restrict__ W, unsigned short* __restrict__ Th,
    int K, int Nfull, int n0off, int zoff, long long zdststep)
{
  __shared__ float tile[32][33];
  int z = blockIdx.z;
  unsigned short* T = Th + (long long)z * zdststep;
  int ncol = n0off + z * zoff;
  int n0 = blockIdx.x * 32, k0 = blockIdx.y * 32;
  int tx = threadIdx.x & 31, ty4 = (threadIdx.x >> 5) * 4;
  #pragma unroll
  for (int i = 0; i < 4; ++i)
    tile[ty4 + i][tx] = W[(long long)(k0 + ty4 + i) * Nfull + ncol + n0 + tx];
  __syncthreads();
  #pragma unroll
  for (int i = 0; i < 4; ++i)
    T[(long long)(n0 + ty4 + i) * K + k0 + tx] = f2bfu(tile[tx][ty4 + i]);
}

// ------ 5 small weights [768][768] -> bf16 [768][768]^T planes --------------
__global__ __launch_bounds__(256) void cvt_w5(
    const float* __restrict__ Wa, const float* __restrict__ Wb,
    const float* __restrict__ Wc, const float* __restrict__ Wd,
    const float* __restrict__ We, unsigned short* __restrict__ Th)
{
  __shared__ float tile[32][33];
  const float* srcs[5] = {Wa, Wb, Wc, Wd, We};
  const float* W = srcs[blockIdx.z];
  unsigned short* T = Th + (long long)blockIdx.z * (768 * 768);
  int n0 = blockIdx.x * 32, k0 = blockIdx.y * 32;
  int tx = threadIdx.x & 31, ty4 = (threadIdx.x >> 5) * 4;
  #pragma unroll
  for (int i = 0; i < 4; ++i)
    tile[ty4 + i][tx] = W[(long long)(k0 + ty4 + i) * 768 + n0 + tx];
  __syncthreads();
  #pragma unroll
  for (int i = 0; i < 4; ++i)
    T[(long long)(n0 + ty4 + i) * 768 + k0 + tx] = f2bfu(tile[tx][ty4 + i]);
}

// ---------------- f32 -> bf16 copy (vectorized) -----------------------------
__global__ __launch_bounds__(256) void cvt_bf_kernel(
    const float* __restrict__ in, unsigned short* __restrict__ out, long long n)
{
  long long i = ((long long)blockIdx.x * 256 + threadIdx.x) * 4;
  if (i < n) {
    float4 v = *reinterpret_cast<const float4*>(&in[i]);
    ushort4 o;
    o.x = f2bfu(v.x); o.y = f2bfu(v.y); o.z = f2bfu(v.z); o.w = f2bfu(v.w);
    *reinterpret_cast<ushort4*>(&out[i]) = o;
  }
}

// -------- f32 vector GEMM (order-critical): 512 thr, LDS double-buffer ------
__global__ __launch_bounds__(512) void gemm_k(
    const float* __restrict__ A, int a_rpb, long long a_bstride,
    const float* __restrict__ W, int wst,
    float* __restrict__ Cf, int c_ld, int M, int K)
{
  __shared__ float As[2][16][132];
  __shared__ float Ws[2][16][132];
  int t = threadIdx.x;
  long long bm = (long long)blockIdx.y * 128;
  long long bn = (long long)blockIdx.x * 128;
  float acc[4][8] = {};
  int wid = t >> 6, lane = t & 63;
  int tm = (wid & 3) * 32 + (lane >> 3) * 4;
  int tn = (wid >> 2) * 64 + (lane & 7) * 8;
  int idx = t << 2;
  int am = idx >> 4, ak = idx & 15;
  int wk = idx >> 7, wn2 = idx & 127;
  long long r = bm + am;
  long long abase = (r / a_rpb) * a_bstride + (r % a_rpb) * (long long)K;
  float4 a4 = *reinterpret_cast<const float4*>(A + abase + ak);
  float4 w4 = *reinterpret_cast<const float4*>(W + (long long)wk * wst + bn + wn2);
  As[0][ak + 0][am] = a4.x; As[0][ak + 1][am] = a4.y;
  As[0][ak + 2][am] = a4.z; As[0][ak + 3][am] = a4.w;
  *reinterpret_cast<float4*>(&Ws[0][wk][wn2]) = w4;
  __syncthreads();
  int cur = 0;
  for (int k0 = 0; k0 < K; k0 += 16) {
    bool more = (k0 + 16 < K);
    if (more) {
      a4 = *reinterpret_cast<const float4*>(A + abase + k0 + 16 + ak);
      w4 = *reinterpret_cast<const float4*>(W + (long long)(k0 + 16 + wk) * wst + bn + wn2);
    }
    #pragma unroll
    for (int kk = 0; kk < 16; ++kk) {
      float a[4], w[8];
      *reinterpret_cast<float4*>(a)     = *reinterpret_cast<const float4*>(&As[cur][kk][tm]);
      *reinterpret_cast<float4*>(w)     = *reinterpret_cast<const float4*>(&Ws[cur][kk][tn]);
      *reinterpret_cast<float4*>(w + 4) = *reinterpret_cast<const float4*>(&Ws[cur][kk][tn + 4]);
      #pragma unroll
      for (int i = 0; i < 4; ++i)
        #pragma unroll
        for (int j = 0; j < 8; ++j)
          acc[i][j] = fmaf(a[i], w[j], acc[i][j]);
    }
    if (more) {
      As[cur ^ 1][ak + 0][am] = a4.x; As[cur ^ 1][ak + 1][am] = a4.y;
      As[cur ^ 1][ak + 2][am] = a4.z; As[cur ^ 1][ak + 3][am] = a4.w;
      *reinterpret_cast<float4*>(&Ws[cur ^ 1][wk][wn2]) = w4;
    }
    __syncthreads();
    cur ^= 1;
  }
  #pragma unroll
  for (int i = 0; i < 4; ++i) {
    long long crow = (bm + tm + i) * c_ld;
    #pragma unroll
    for (int j = 0; j < 8; ++j)
      Cf[crow + bn + tn + j] = acc[i][j];
  }
}

// -------- MFMA GEMM v2 (m97 pattern): global_load_lds + linear LDS ----------
__global__ __launch_bounds__(256) void gemm_mfma(
    const unsigned short* __restrict__ A, const unsigned short* __restrict__ Bt,
    const float* __restrict__ bias, const float* __restrict__ resid,
    float* __restrict__ Cf, int ldf,
    unsigned short* __restrict__ Cb, int ldb, int colsplit,
    int M, int N, int K,
    int c_rpb, long long c_bstride, int c_row0, int act)
{
  __shared__ unsigned short As[128 * 32], Bs[128 * 32];
  int t = threadIdx.x;
  long long bm = (long long)blockIdx.y * 128;
  long long bn = (long long)blockIdx.x * 128;
  int wid = t >> 6, lane = t & 63;
  int wr = (wid >> 1) << 6, wc = (wid & 1) << 6;
  int e0 = (wid << 9) + lane * 8;
  int e1 = ((4 + wid) << 9) + lane * 8;
  int r0 = e0 >> 5, c0 = e0 & 31;
  int r1 = e1 >> 5, c1 = e1 & 31;
  unsigned short* As0 = &As[(long long)(wid << 9)];
  unsigned short* As1 = &As[(long long)((4 + wid) << 9)];
  unsigned short* Bs0 = &Bs[(long long)(wid << 9)];
  unsigned short* Bs1 = &Bs[(long long)((4 + wid) << 9)];
  const unsigned short* Ar0 = A + (bm + r0) * (long long)K + c0;
  const unsigned short* Ar1 = A + (bm + r1) * (long long)K + c1;
  const unsigned short* Br0 = Bt + (bn + r0) * (long long)K + c0;
  const unsigned short* Br1 = Bt + (bn + r1) * (long long)K + c1;
  f32x4 acc[4][4];
  #pragma unroll
  for (int m = 0; m < 4; ++m)
    #pragma unroll
    for (int n = 0; n < 4; ++n) acc[m][n] = (f32x4){0.f, 0.f, 0.f, 0.f};
  int ra = (wr + (lane & 15)) * 32 + ((lane >> 4) << 3);
  int rb = (wc + (lane & 15)) * 32 + ((lane >> 4) << 3);
  for (int k0 = 0; k0 < K; k0 += 32) {
    gload16(Ar0 + k0, As0);
    gload16(Ar1 + k0, As1);
    gload16(Br0 + k0, Bs0);
    gload16(Br1 + k0, Bs1);
    __syncthreads();
    short8v a[4], b[4];
    #pragma unroll
    for (int m = 0; m < 4; ++m) {
      a[m] = *reinterpret_cast<const short8v*>(&As[ra + m * 512]);
      b[m] = *reinterpret_cast<const short8v*>(&Bs[rb + m * 512]);
    }
    #pragma unroll
    for (int m = 0; m < 4; ++m)
      #pragma unroll
      for (int n = 0; n < 4; ++n)
        acc[m][n] = __builtin_amdgcn_mfma_f32_16x16x32_bf16(a[m], b[n], acc[m][n], 0, 0, 0);
    __syncthreads();
  }
  int ro = (lane >> 4) << 2, co = lane & 15;
  #pragma unroll
  for (int m = 0; m < 4; ++m) {
    #pragma unroll
    for (int j = 0; j < 4; ++j) {
      long long r = bm + wr + m * 16 + ro + j;
      long long base = (r / c_rpb) * c_bstride + (long long)((int)(r % c_rpb) + c_row0) * ldf;
      #pragma unroll
      for (int n = 0; n < 4; ++n) {
        long long c = bn + wc + n * 16 + co;
        float v = acc[m][n][j];
        if (bias) v += bias[c];
        if (act) v = 0.5f * v * (1.f + erff(v * 0.70710678118654752f));
        if (resid) v += resid[base + c];
        if (c < colsplit) Cf[base + c] = v;
        else Cb[r * ldb + (c - colsplit)] = f2bfu(v);
      }
    }
  }
}

// ======== MFMA flash attention (value path) — round-8 exact =================
template<int NKV, int NW, int PROBS, int KF32>
__global__ __launch_bounds__(NW * 64) void attn_mfma(
    const unsigned short* __restrict__ q, int q_rs, int q_bs, int q_off,
    const void* __restrict__ kv, int k_rs,
    const unsigned short* __restrict__ v, int v_rs,
    unsigned short* __restrict__ xab, int xa_rs, int xa_bs, int xa_off,
    float* __restrict__ probs, int NQtot)
{
  constexpr int KST = 68;
  constexpr int VST = NKV + 4;
  constexpr int NT_K = NKV / 16;
  constexpr int NTH = NW * 64;
  __shared__ unsigned short ksh[NKV * KST];
  __shared__ unsigned short qsh[NW * 16 * KST];
  __shared__ unsigned short vsh[64 * VST];
  __shared__ float ldsT[PROBS ? NW * 16 * 17 : 1];
  int bh = blockIdx.x, b = bh / HH, h = bh % HH;
  int rb = blockIdx.y * (NW * 16);
  int t = threadIdx.x;
  const float* kf = (const float*)kv;
  const unsigned short* ku = (const unsigned short*)kv;
  for (int i = t; i < NKV * 64; i += NTH) {
    int kr = i >> 6, d = i & 63;
    long long gi = (long long)(b * NKV + kr);
    ksh[kr * KST + d] = KF32 ? f2bfu(kf[gi * k_rs + h * DHD + d])
                             : ku[gi * k_rs + h * DHD + d];
    int kp = (kr & ~31) | (((kr >> 2) & 3) << 3) | (((kr >> 4) & 1) << 2) | (kr & 3);
    vsh[d * VST + kp] = v[gi * v_rs + h * DHD + d];
  }
  for (int i = t; i < NW * 16 * 64; i += NTH) {
    int qr = i >> 6, d = i & 63;
    int qg = rb + qr;
    qsh[qr * KST + d] = (qg < NQtot)
      ? q[(long long)(b * q_bs + q_off + qg) * q_rs + h * DHD + d] : (unsigned short)0;
  }
  __syncthreads();
  int wid = t >> 6, lane = t & 63;
  int l15 = lane & 15, lg = lane >> 4;
  short8v bq[2];
  #pragma unroll
  for (int ks = 0; ks < 2; ++ks)
    bq[ks] = *reinterpret_cast<const short8v*>(&qsh[(wid * 16 + l15) * KST + ks * 32 + lg * 8]);
  f32x4 s[NT_K];
  #pragma unroll
  for (int mt = 0; mt < NT_K; ++mt) s[mt] = (f32x4){0.f, 0.f, 0.f, 0.f};
  #pragma unroll
  for (int mt = 0; mt < NT_K; ++mt)
    #pragma unroll
    for (int ks = 0; ks < 2; ++ks) {
      short8v ka = *reinterpret_cast<const short8v*>(&ksh[(mt * 16 + l15) * KST + ks * 32 + lg * 8]);
      s[mt] = __builtin_amdgcn_mfma_f32_16x16x32_bf16(ka, bq[ks], s[mt], 0, 0, 0);
    }
  float m = -3.4e38f;
  #pragma unroll
  for (int mt = 0; mt < NT_K; ++mt)
    #pragma unroll
    for (int j = 0; j < 4; ++j) { s[mt][j] *= 0.125f; m = fmaxf(m, s[mt][j]); }
  m = fmaxf(m, __shfl_xor(m, 16)); m = fmaxf(m, __shfl_xor(m, 32));
  float ss = 0.f;
  #pragma unroll
  for (int mt = 0; mt < NT_K; ++mt)
    #pragma unroll
    for (int j = 0; j < 4; ++j) { s[mt][j] = __expf(s[mt][j] - m); ss += s[mt][j]; }
  ss += __shfl_xor(ss, 16); ss += __shfl_xor(ss, 32);
  float inv = 1.f / ss;
  #pragma unroll
  for (int mt = 0; mt < NT_K; ++mt)
    #pragma unroll
    for (int j = 0; j < 4; ++j) s[mt][j] *= inv;
  if (PROBS) {
    float* lT = &ldsT[wid * 16 * 17];
    #pragma unroll
    for (int mt = 0; mt < NT_K; ++mt) {
      #pragma unroll
      for (int j = 0; j < 4; ++j) lT[l15 * 17 + lg * 4 + j] = s[mt][j];
      #pragma unroll
      for (int m4 = 0; m4 < 4; ++m4) {
        int qg = rb + wid * 16 + m4 * 4 + lg;
        if (qg < NQtot)
          probs[((long long)(bh * q_bs + q_off + qg)) * NKV + mt * 16 + l15] =
              lT[(m4 * 4 + lg) * 17 + l15];
      }
    }
  }
  f32x4 o[4];
  #pragma unroll
  for (int nt = 0; nt < 4; ++nt) o[nt] = (f32x4){0.f, 0.f, 0.f, 0.f};
  #pragma unroll
  for (int c = 0; c < NKV / 32; ++c) {
    short8v a8;
    #pragma unroll
    for (int j = 0; j < 4; ++j) {
      a8[j]     = (short)f2bfu(s[2 * c][j]);
      a8[4 + j] = (short)f2bfu(s[2 * c + 1][j]);
    }
    #pragma unroll
    for (int nt = 0; nt < 4; ++nt) {
      short8v bv = *reinterpret_cast<const short8v*>(&vsh[(nt * 16 + l15) * VST + c * 32 + lg * 8]);
      o[nt] = __builtin_amdgcn_mfma_f32_16x16x32_bf16(a8, bv, o[nt], 0, 0, 0);
    }
  }
  #pragma unroll
  for (int nt = 0; nt < 4; ++nt)
    #pragma unroll
    for (int j = 0; j < 4; ++j) {
      int qg = rb + wid * 16 + lg * 4 + j;
      if (qg < NQtot)
        xab[(long long)(b * xa_bs + xa_off + qg) * xa_rs + h * DHD + nt * 16 + l15] =
            f2bfu(o[nt][j]);
    }
}

// ---- f32 attention for template rows (q<64): r10/r11-exact (known-good) ----
__global__ __launch_bounds__(1024) void attn_tmpl(
    const float* __restrict__ qt, const float* __restrict__ kf,
    const unsigned short* __restrict__ vb,
    unsigned short* __restrict__ xab, float* __restrict__ probs,
    float* __restrict__ atp)
{
  constexpr int VST = NN + 4;
  __shared__ float ksh[NN * 65];
  __shared__ unsigned short vsh[64 * VST];
  __shared__ float pss[16][NN];
  __shared__ float qsh[16][64];
  int bh = blockIdx.x, b = bh / HH, h = bh % HH;
  int t = threadIdx.x;
  for (int i = t; i < NN * 64; i += 1024) {
    int rr = i >> 6, d = i & 63;
    long long gi = (long long)(b * NN + rr);
    ksh[rr * 65 + d] = kf[gi * 768 + h * DHD + d];
    vsh[d * VST + rr] = vb[gi * 1536 + h * DHD + d];
  }
  __syncthreads();
  int wid = t >> 6, lane = t & 63;
  float at[4] = {};
  for (int q = wid; q < NT; q += 16) {
    qsh[wid][lane] = qt[(long long)(b * NT + q) * 768 + h * DHD + lane];
    float s[5];
    #pragma unroll
    for (int r = 0; r < 5; ++r) s[r] = 0.f;
    const float* kp = ksh + lane * 65;
    #pragma unroll 16
    for (int d = 0; d < 64; ++d) {
      float qd = qsh[wid][d];
      #pragma unroll
      for (int r = 0; r < 5; ++r)
        s[r] = fmaf(qd, kp[(r << 6) * 65 + d], s[r]);
    }
    float m = -3.4e38f;
    #pragma unroll
    for (int r = 0; r < 5; ++r) { s[r] *= 0.125f; m = fmaxf(m, s[r]); }
    #pragma unroll
    for (int off = 32; off > 0; off >>= 1) m = fmaxf(m, __shfl_xor(m, off));
    float ss = 0.f;
    #pragma unroll
    for (int r = 0; r < 5; ++r) { s[r] = __expf(s[r] - m); ss += s[r]; }
    #pragma unroll
    for (int off = 32; off > 0; off >>= 1) ss += __shfl_xor(ss, off);
    float inv = 1.f / ss;
    long long pb = ((long long)(bh * NN) + q) * NN;
    #pragma unroll
    for (int r = 0; r < 5; ++r) {
      float p = s[r] * inv;
      s[r] = p;
      pss[wid][lane + (r << 6)] = p;
      probs[pb + lane + (r << 6)] = p;
    }
    #pragma unroll
    for (int r = 1; r < 5; ++r) at[r - 1] += s[r];
    float acc = 0.f;
    const unsigned short* vp = vsh + lane * VST;
    #pragma unroll 8
    for (int j = 0; j < NN; j += 4) {
      float4 p4 = *reinterpret_cast<const float4*>(&pss[wid][j]);
      ushort4 v4 = *reinterpret_cast<const ushort4*>(&vp[j]);
      acc = fmaf(p4.x, bf2f(v4.x), acc);
      acc = fmaf(p4.y, bf2f(v4.y), acc);
      acc = fmaf(p4.z, bf2f(v4.z), acc);
      acc = fmaf(p4.w, bf2f(v4.w), acc);
    }
    xab[(long long)(b * NN + q) * 768 + h * DHD + lane] = f2bfu(acc);
  }
  #pragma unroll
  for (int r = 1; r < 5; ++r) pss[wid][lane + ((r - 1) << 6)] = at[r - 1];
  __syncthreads();
  if (t < 256) {
    float v = 0.f;
    #pragma unroll
    for (int w = 0; w < 16; ++w) v += pss[w][t];
    atp[(long long)bh * 256 + t] = v;
  }
}

// ---- Per-batch argsort(-attn_t), stable; emit keep/removed -----------------
__global__ __launch_bounds__(256) void sort_kernel(
    const float* __restrict__ atp, const int* __restrict__ gis,
    float* __restrict__ keep_out, float* __restrict__ rem_out,
    int* __restrict__ topk)
{
  int b = blockIdx.x, t = threadIdx.x;
  __shared__ float sv[256];
  __shared__ int   si[256];
  float v = 0.f;
  for (int h = 0; h < HH; ++h) v += atp[((long long)(b * HH + h) << 8) + t];
  sv[t] = v; si[t] = t;
  __syncthreads();
  for (int k = 2; k <= 256; k <<= 1) {
    for (int j = k >> 1; j > 0; j >>= 1) {
      int ixj = t ^ j;
      if (ixj > t) {
        float va = sv[t], vb2 = sv[ixj];
        int ia = si[t], ib = si[ixj];
        bool after = (va < vb2) || (va == vb2 && ia > ib);
        bool dirUp = ((t & k) == 0);
        if (after == dirUp) { sv[t] = vb2; sv[ixj] = va; si[t] = ib; si[ixj] = ia; }
      }
      __syncthreads();
    }
  }
  int o = si[t];
  if (t < LK) {
    topk[b * LK + t] = o;
    keep_out[b * LK + t] = (float)gis[(b << 8) + o];
  } else {
    rem_out[b * NREM + (t - LK)] = (float)gis[(b << 8) + o];
  }
}

__global__ __launch_bounds__(256) void gather_kernel(
    const float* __restrict__ x1, const int* __restrict__ topk, float* __restrict__ x2)
{
  int r = blockIdx.x, t = threadIdx.x;
  int b = r / 244, rr = r % 244;
  int src = (rr < NT) ? rr : (NT + topk[b * LK + (rr - NT)]);
  const float* s = x1 + (long long)(b * NN + src) * DD;
  float* d = x2 + (long long)r * DD;
  d[t] = s[t]; d[256 + t] = s[256 + t]; d[512 + t] = s[512 + t];
}

__global__ void git_kernel(const int* __restrict__ git, float* __restrict__ o)
{
  int i = blockIdx.x * 256 + threadIdx.x;
  if (i < BB * NT) o[i] = (float)git[i];
}

extern "C" void kernel_launch(void* const* d_in, const int* in_sizes, int n_in,
                              void* d_out, int out_size, void* d_ws, size_t ws_size,
                              hipStream_t stream) {
  (void)in_sizes; (void)n_in; (void)out_size; (void)ws_size;
  const float* x    = (const float*)d_in[0];
  const float* ps   = (const float*)d_in[1];
  const int*   git  = (const int*)d_in[2];
  const int*   gis  = (const int*)d_in[3];
  const float* g1   = (const float*)d_in[4];
  const float* b1   = (const float*)d_in[5];
  const float* Wqkv = (const float*)d_in[6];
  const float* Wproj= (const float*)d_in[7];
  const float* bproj= (const float*)d_in[8];
  const float* gt   = (const float*)d_in[9];
  const float* bt   = (const float*)d_in[10];
  const float* Wq   = (const float*)d_in[11];
  const float* Wk   = (const float*)d_in[12];
  const float* Wv   = (const float*)d_in[13];
  const float* Wtp  = (const float*)d_in[14];
  const float* btp  = (const float*)d_in[15];
  const float* g2   = (const float*)d_in[16];
  const float* b2   = (const float*)d_in[17];
  const float* W1   = (const float*)d_in[18];
  const float* b1m  = (const float*)d_in[19];
  const float* W2   = (const float*)d_in[20];
  const float* b2m  = (const float*)d_in[21];
  float* wsf = (float*)d_ws;
  float* out = (float*)d_out;
  unsigned short* WQVT = (unsigned short*)(wsf + OFF_WQVT);
  unsigned short* HBp  = (unsigned short*)(wsf + OFF_HB);
  unsigned short* QVp  = (unsigned short*)(wsf + OFF_QV);
  unsigned short* XAp  = (unsigned short*)(wsf + OFF_XA);
  unsigned short* WSMp = (unsigned short*)(wsf + OFF_WSM);
  unsigned short* WTS2 = (unsigned short*)(wsf + OFF_WTS2);
  unsigned short* SNp  = (unsigned short*)(wsf + OFF_SN);
  unsigned short* PSBp = (unsigned short*)(wsf + OFF_PSB);
  unsigned short* QT2p = (unsigned short*)(wsf + OFF_QT2);
  unsigned short* KTp  = (unsigned short*)(wsf + OFF_KT);
  unsigned short* VTp  = (unsigned short*)(wsf + OFF_VT);
  unsigned short* SAp  = (unsigned short*)(wsf + OFF_SA);
  unsigned short* H2p  = (unsigned short*)(wsf + OFF_H2);
  unsigned short* MIDp = (unsigned short*)(wsf + OFF_MIDB);
  #define WSLOT(i) (WSMp + (long long)(i) * 768 * 768)

  // S0a: Wqkv q-part and v-part -> 2 transposed bf16 planes
  hipLaunchKernelGGL(cvt_wt, dim3(24, 24, 2), dim3(256), 0, stream,
                     Wqkv, WQVT, DD, 3 * DD, 0, 1536, (long long)768 * 768);
  // S0b: 5 small weights -> transposed planes
  hipLaunchKernelGGL(cvt_w5, dim3(24, 24, 5), dim3(256), 0, stream,
                     Wproj, Wq, Wk, Wv, Wtp, WSMp);
  // S1: h = LN(x) -> f32 HF + bf16 HB
  hipLaunchKernelGGL((ln_kernel<3>), dim3(BB * NN), dim3(256), 0, stream,
                     x, wsf + OFF_HF, HBp, g1, b1, BB * NN, 0LL, 0);
  // S2a: k = h @ Wqkv[:,768:1536]  (f32, exact)
  hipLaunchKernelGGL(gemm_k, dim3(6, 80), dim3(512), 0, stream,
                     wsf + OFF_HF, BB * NN, 0LL, Wqkv + 768, 3 * DD,
                     wsf + OFF_KF, DD, BB * NN, DD);
  // S2b: q_template = h[template rows] @ Wqkv[:,0:768]
  hipLaunchKernelGGL(gemm_k, dim3(6, 16), dim3(512), 0, stream,
                     wsf + OFF_HF, NT, (long long)NN * DD, Wqkv, 3 * DD,
                     wsf + OFF_QTF, DD, BB * NT, DD);
  // S2c: [q|v] = h(bf16) @ [Wq-part|Wv-part]  (MFMA v2)
  hipLaunchKernelGGL(gemm_mfma, dim3(12, 80), dim3(256), 0, stream,
                     HBp, WQVT, (const float*)nullptr, (const float*)nullptr,
                     (float*)nullptr, 1, QVp, 1536, 0,
                     BB * NN, 1536, DD, BB * NN, 0LL, 0, 0);
  // S3B: MFMA attention rows 64..319 -> probs, xa
  hipLaunchKernelGGL((attn_mfma<NN, 8, 1, 1>), dim3(BB * HH, 2), dim3(512), 0, stream,
                     QVp, 1536, NN, NT,
                     (const void*)(wsf + OFF_KF), DD,
                     QVp + 768, 1536,
                     XAp, DD, NN, NT,
                     out + O_ATTN, 256);
  // S3A: f32 attention rows <64 -> probs, xa, attn_t
  hipLaunchKernelGGL(attn_tmpl, dim3(BB * HH), dim3(1024), 0, stream,
                     wsf + OFF_QTF, wsf + OFF_KF, QVp + 768,
                     XAp, out + O_ATTN, wsf + OFF_ATP);
  // S4: x1 = x + xa @ Wproj + bproj
  hipLaunchKernelGGL(gemm_mfma, dim3(6, 80), dim3(256), 0, stream,
                     XAp, WSLOT(0), bproj, x,
                     wsf + OFF_X1, DD, (unsigned short*)nullptr, 1, DD,
                     BB * NN, DD, DD, BB * NN, 0LL, 0, 0);
  // S5/S6/S7
  hipLaunchKernelGGL(sort_kernel, dim3(BB), dim3(256), 0, stream,
                     wsf + OFF_ATP, gis, out + O_KEEP, out + O_REM,
                     (int*)(wsf + OFF_TOPK));
  hipLaunchKernelGGL(git_kernel, dim3((BB * NT + 255) / 256), dim3(256), 0, stream,
                     git, out + O_GIT);
  hipLaunchKernelGGL(gather_kernel, dim3(BB * 244), dim3(256), 0, stream,
                     wsf + OFF_X1, (const int*)(wsf + OFF_TOPK), wsf + OFF_X2);
  // S7.5: ps -> bf16 (QV region dead)
  hipLaunchKernelGGL(cvt_bf_kernel, dim3(6144), dim3(256), 0, stream,
                     ps, PSBp, (long long)BB * NPS * DD);
  // S8: sn = LN(s) -> bf16
  hipLaunchKernelGGL((ln_kernel<1>), dim3(BB * LK), dim3(256), 0, stream,
                     wsf + OFF_X2, (float*)nullptr, SNp, gt, bt, LK, (long long)244 * DD, NT);
  // S9: qT = sn @ Wq -> bf16
  hipLaunchKernelGGL(gemm_mfma, dim3(6, 45), dim3(256), 0, stream,
                     SNp, WSLOT(1), (const float*)nullptr, (const float*)nullptr,
                     (float*)nullptr, 1, QT2p, DD, 0,
                     BB * LK, DD, DD, BB * LK, 0LL, 0, 0);
  // S10: kT = ps @ Wk -> bf16
  hipLaunchKernelGGL(gemm_mfma, dim3(6, 64), dim3(256), 0, stream,
                     PSBp, WSLOT(2), (const float*)nullptr, (const float*)nullptr,
                     (float*)nullptr, 1, KTp, DD, 0,
                     BB * NPS, DD, DD, BB * NPS, 0LL, 0, 0);
  // S11: vT = ps @ Wv -> bf16
  hipLaunchKernelGGL(gemm_mfma, dim3(6, 64), dim3(256), 0, stream,
                     PSBp, WSLOT(3), (const float*)nullptr, (const float*)nullptr,
                     (float*)nullptr, 1, VTp, DD, 0,
                     BB * NPS, DD, DD, BB * NPS, 0LL, 0, 0);
  // S12: stage-2 attention (MFMA) -> sa bf16
  hipLaunchKernelGGL((attn_mfma<NPS, 8, 0, 0>), dim3(BB * HH, 2), dim3(512), 0, stream,
                     QT2p, DD, LK, 0,
                     (const void*)KTp, DD,
                     VTp, DD,
                     SAp, DD, LK, 0,
                     (float*)nullptr, LK);
  // S13: s2 = s + sa @ Wtp + btp (into x2 rows 64..243)
  hipLaunchKernelGGL(gemm_mfma, dim3(6, 45), dim3(256), 0, stream,
                     SAp, WSLOT(4), btp, wsf + OFF_X2,
                     wsf + OFF_X2, DD, (unsigned short*)nullptr, 1, DD,
                     BB * LK, DD, DD, LK, (long long)244 * DD, NT, 0);
  // S14: h2 = LN(x2) -> bf16
  hipLaunchKernelGGL((ln_kernel<1>), dim3(BB * 244), dim3(256), 0, stream,
                     wsf + OFF_X2, (float*)nullptr, H2p, g2, b2, BB * 244, 0LL, 0);
  // S15: mid = gelu(h2 @ W1 + b1m) -> bf16
  hipLaunchKernelGGL(cvt_wt, dim3(96, 24, 1), dim3(256), 0, stream,
                     W1, WTS2, DD, 4 * DD, 0, 0, 0LL);
  hipLaunchKernelGGL(gemm_mfma, dim3(24, 61), dim3(256), 0, stream,
                     H2p, WTS2, b1m, (const float*)nullptr,
                     (float*)nullptr, 1, MIDp, 4 * DD, 0,
                     BB * 244, 4 * DD, DD, BB * 244, 0LL, 0, 1);
  // S16: x_out = x2 + mid @ W2 + b2m -> f32 d_out
  hipLaunchKernelGGL(cvt_wt, dim3(24, 96, 1), dim3(256), 0, stream,
                     W2, WTS2, 4 * DD, DD, 0, 0, 0LL);
  hipLaunchKernelGGL(gemm_mfma, dim3(6, 61), dim3(256), 0, stream,
                     MIDp, WTS2, b2m, wsf + OFF_X2,
                     out + O_X, DD, (unsigned short*)nullptr, 1, DD,
                     BB * 244, DD, 4 * DD, BB * 244, 0LL, 0, 0);
}

// Round 16
// 1033.406 us; speedup vs baseline: 1.4358x; 1.0072x over previous
//
#include <hip/hip_runtime.h>
#include <hip/hip_bf16.h>

// Problem constants
#define BB 32
#define NT 64
#define NS 256
#define NN 320
#define NPS 256
#define DD 768
#define HH 12
#define DHD 64
#define LK 180
#define NREM 76

// ws layout (float-element offsets). Peak 32.18M f = 128.7MB.
#define OFF_HF    0LL
#define OFF_KF    7864320LL
#define OFF_QTF   15728640LL
#define OFF_QV    17301504LL
#define OFF_WQVT  25165824LL
#define OFF_HB    26000000LL
#define OFF_XA    0LL
#define OFF_X1    12000000LL
#define OFF_X2    0LL
#define OFF_SN    6000000LL
#define OFF_PSB   17301504LL
#define OFF_QT2   20500000LL
#define OFF_KT    22800000LL
#define OFF_VT    26000000LL
#define OFF_SA    6000000LL
#define OFF_H2    12000000LL
#define OFF_MIDB  15000000LL
#define OFF_WTS2  29300000LL
#define OFF_ATP   30500000LL
#define OFF_TOPK  30600000LL
#define OFF_WSM   30700000LL

// d_out (f32) offsets: (x, git, keep, removed, attn)
#define O_X    0LL
#define O_GIT  5996544LL
#define O_KEEP 5998592LL
#define O_REM  6004352LL
#define O_ATTN 6006784LL

typedef __attribute__((ext_vector_type(8))) short short8v;
typedef __attribute__((ext_vector_type(4))) float f32x4;

__device__ __forceinline__ float bf2f(unsigned short u) {
  return __uint_as_float((unsigned)u << 16);
}
__device__ __forceinline__ unsigned short f2bfu(float f) {
  __hip_bfloat16 h = __float2bfloat16(f);
  return *reinterpret_cast<unsigned short*>(&h);
}
__device__ __forceinline__ void gload16(const unsigned short* g, unsigned short* l) {
  __builtin_amdgcn_global_load_lds(
      (const __attribute__((address_space(1))) unsigned int*)g,
      (__attribute__((address_space(3))) unsigned int*)l, 16, 0, 0);
}

// ---------------- LayerNorm. OMODE: 0=f32, 1=bf16, 3=both -------------------
template<int OMODE>
__global__ __launch_bounds__(256) void ln_kernel(
    const float* __restrict__ in, float* __restrict__ outf,
    unsigned short* __restrict__ outh,
    const float* __restrict__ g, const float* __restrict__ b,
    int rpb, long long bstride, int row0)
{
  int r = blockIdx.x, t = threadIdx.x;
  long long base = (long long)(r / rpb) * bstride + (long long)(r % rpb + row0) * DD;
  float v0 = in[base + t], v1 = in[base + 256 + t], v2 = in[base + 512 + t];
  __shared__ float red[256];
  red[t] = v0 + v1 + v2;
  __syncthreads();
  #pragma unroll
  for (int off = 128; off > 0; off >>= 1) { if (t < off) red[t] += red[t + off]; __syncthreads(); }
  float mean = red[0] * (1.f / 768.f);
  __syncthreads();
  float d0 = v0 - mean, d1 = v1 - mean, d2 = v2 - mean;
  red[t] = d0 * d0 + d1 * d1 + d2 * d2;
  __syncthreads();
  #pragma unroll
  for (int off = 128; off > 0; off >>= 1) { if (t < off) red[t] += red[t + off]; __syncthreads(); }
  float rstd = rsqrtf(red[0] * (1.f / 768.f) + 1e-5f);
  long long ob = (long long)r * DD;
  float o0 = d0 * rstd * g[t]       + b[t];
  float o1 = d1 * rstd * g[256 + t] + b[256 + t];
  float o2 = d2 * rstd * g[512 + t] + b[512 + t];
  if (OMODE == 0 || OMODE == 3) {
    outf[ob + t] = o0; outf[ob + 256 + t] = o1; outf[ob + 512 + t] = o2;
  }
  if (OMODE == 1 || OMODE == 3) {
    outh[ob + t] = f2bfu(o0); outh[ob + 256 + t] = f2bfu(o1); outh[ob + 512 + t] = f2bfu(o2);
  }
}

// ------ Transpose+convert: W f32 [K][Nfull] -> bf16 [N][K]; z-planes --------
__global__ __launch_bounds__(256) void cvt_wt(
    const float* __restrict__ W, unsigned short* __restrict__ Th,
    int K, int Nfull, int n0off, int zoff, long long zdststep)
{
  __shared__ float tile[32][33];
  int z = blockIdx.z;
  unsigned short* T = Th + (long long)z * zdststep;
  int ncol = n0off + z * zoff;
  int n0 = blockIdx.x * 32, k0 = blockIdx.y * 32;
  int tx = threadIdx.x & 31, ty4 = (threadIdx.x >> 5) * 4;
  #pragma unroll
  for (int i = 0; i < 4; ++i)
    tile[ty4 + i][tx] = W[(long long)(k0 + ty4 + i) * Nfull + ncol + n0 + tx];
  __syncthreads();
  #pragma unroll
  for (int i = 0; i < 4; ++i)
    T[(long long)(n0 + ty4 + i) * K + k0 + tx] = f2bfu(tile[tx][ty4 + i]);
}

// ------ 5 small weights [768][768] -> bf16 [768][768]^T planes --------------
__global__ __launch_bounds__(256) void cvt_w5(
    const float* __restrict__ Wa, const float* __restrict__ Wb,
    const float* __restrict__ Wc, const float* __restrict__ Wd,
    const float* __restrict__ We, unsigned short* __restrict__ Th)
{
  __shared__ float tile[32][33];
  const float* srcs[5] = {Wa, Wb, Wc, Wd, We};
  const float* W = srcs[blockIdx.z];
  unsigned short* T = Th + (long long)blockIdx.z * (768 * 768);
  int n0 = blockIdx.x * 32, k0 = blockIdx.y * 32;
  int tx = threadIdx.x & 31, ty4 = (threadIdx.x >> 5) * 4;
  #pragma unroll
  for (int i = 0; i < 4; ++i)
    tile[ty4 + i][tx] = W[(long long)(k0 + ty4 + i) * 768 + n0 + tx];
  __syncthreads();
  #pragma unroll
  for (int i = 0; i < 4; ++i)
    T[(long long)(n0 + ty4 + i) * 768 + k0 + tx] = f2bfu(tile[tx][ty4 + i]);
}

// ---------------- f32 -> bf16 copy (vectorized) -----------------------------
__global__ __launch_bounds__(256) void cvt_bf_kernel(
    const float* __restrict__ in, unsigned short* __restrict__ out, long long n)
{
  long long i = ((long long)blockIdx.x * 256 + threadIdx.x) * 4;
  if (i < n) {
    float4 v = *reinterpret_cast<const float4*>(&in[i]);
    ushort4 o;
    o.x = f2bfu(v.x); o.y = f2bfu(v.y); o.z = f2bfu(v.z); o.w = f2bfu(v.w);
    *reinterpret_cast<ushort4*>(&out[i]) = o;
  }
}

// -------- f32 vector GEMM (order-critical): r11-exact (known-good 170us) ----
// 512 thr, 128x128x16, reg prefetch, single LDS buffer, kk-ascending order.
__global__ __launch_bounds__(512) void gemm_k(
    const float* __restrict__ A, int a_rpb, long long a_bstride,
    const float* __restrict__ W, int wst,
    float* __restrict__ Cf, int c_ld, int M, int K)
{
  __shared__ float As[16][132];
  __shared__ float Ws[16][132];
  int t = threadIdx.x;
  long long bm = (long long)blockIdx.y * 128;
  long long bn = (long long)blockIdx.x * 128;
  float acc[4][8] = {};
  int wid = t >> 6, lane = t & 63;
  int tm = (wid & 3) * 32 + (lane >> 3) * 4;
  int tn = (wid >> 2) * 64 + (lane & 7) * 8;
  int idx = t << 2;
  int am = idx >> 4, ak = idx & 15;
  int wk = idx >> 7, wn2 = idx & 127;
  long long r = bm + am;
  long long abase = (r / a_rpb) * a_bstride + (r % a_rpb) * (long long)K;
  float4 a4 = *reinterpret_cast<const float4*>(A + abase + ak);
  float4 w4 = *reinterpret_cast<const float4*>(W + (long long)wk * wst + bn + wn2);
  for (int k0 = 0; k0 < K; k0 += 16) {
    As[ak + 0][am] = a4.x; As[ak + 1][am] = a4.y;
    As[ak + 2][am] = a4.z; As[ak + 3][am] = a4.w;
    *reinterpret_cast<float4*>(&Ws[wk][wn2]) = w4;
    __syncthreads();
    if (k0 + 16 < K) {     // prefetch next tile; overlaps FMA block below
      a4 = *reinterpret_cast<const float4*>(A + abase + k0 + 16 + ak);
      w4 = *reinterpret_cast<const float4*>(W + (long long)(k0 + 16 + wk) * wst + bn + wn2);
    }
    #pragma unroll
    for (int kk = 0; kk < 16; ++kk) {
      float a[4], w[8];
      *reinterpret_cast<float4*>(a)     = *reinterpret_cast<const float4*>(&As[kk][tm]);
      *reinterpret_cast<float4*>(w)     = *reinterpret_cast<const float4*>(&Ws[kk][tn]);
      *reinterpret_cast<float4*>(w + 4) = *reinterpret_cast<const float4*>(&Ws[kk][tn + 4]);
      #pragma unroll
      for (int i = 0; i < 4; ++i)
        #pragma unroll
        for (int j = 0; j < 8; ++j)
          acc[i][j] = fmaf(a[i], w[j], acc[i][j]);
    }
    __syncthreads();
  }
  #pragma unroll
  for (int i = 0; i < 4; ++i) {
    long long crow = (bm + tm + i) * c_ld;
    #pragma unroll
    for (int j = 0; j < 8; ++j)
      Cf[crow + bn + tn + j] = acc[i][j];
  }
}

// -------- MFMA GEMM v2 (m97 pattern): global_load_lds + linear LDS ----------
__global__ __launch_bounds__(256) void gemm_mfma(
    const unsigned short* __restrict__ A, const unsigned short* __restrict__ Bt,
    const float* __restrict__ bias, const float* __restrict__ resid,
    float* __restrict__ Cf, int ldf,
    unsigned short* __restrict__ Cb, int ldb, int colsplit,
    int M, int N, int K,
    int c_rpb, long long c_bstride, int c_row0, int act)
{
  __shared__ unsigned short As[128 * 32], Bs[128 * 32];
  int t = threadIdx.x;
  long long bm = (long long)blockIdx.y * 128;
  long long bn = (long long)blockIdx.x * 128;
  int wid = t >> 6, lane = t & 63;
  int wr = (wid >> 1) << 6, wc = (wid & 1) << 6;
  int e0 = (wid << 9) + lane * 8;
  int e1 = ((4 + wid) << 9) + lane * 8;
  int r0 = e0 >> 5, c0 = e0 & 31;
  int r1 = e1 >> 5, c1 = e1 & 31;
  unsigned short* As0 = &As[(long long)(wid << 9)];
  unsigned short* As1 = &As[(long long)((4 + wid) << 9)];
  unsigned short* Bs0 = &Bs[(long long)(wid << 9)];
  unsigned short* Bs1 = &Bs[(long long)((4 + wid) << 9)];
  const unsigned short* Ar0 = A + (bm + r0) * (long long)K + c0;
  const unsigned short* Ar1 = A + (bm + r1) * (long long)K + c1;
  const unsigned short* Br0 = Bt + (bn + r0) * (long long)K + c0;
  const unsigned short* Br1 = Bt + (bn + r1) * (long long)K + c1;
  f32x4 acc[4][4];
  #pragma unroll
  for (int m = 0; m < 4; ++m)
    #pragma unroll
    for (int n = 0; n < 4; ++n) acc[m][n] = (f32x4){0.f, 0.f, 0.f, 0.f};
  int ra = (wr + (lane & 15)) * 32 + ((lane >> 4) << 3);
  int rb = (wc + (lane & 15)) * 32 + ((lane >> 4) << 3);
  for (int k0 = 0; k0 < K; k0 += 32) {
    gload16(Ar0 + k0, As0);
    gload16(Ar1 + k0, As1);
    gload16(Br0 + k0, Bs0);
    gload16(Br1 + k0, Bs1);
    __syncthreads();
    short8v a[4], b[4];
    #pragma unroll
    for (int m = 0; m < 4; ++m) {
      a[m] = *reinterpret_cast<const short8v*>(&As[ra + m * 512]);
      b[m] = *reinterpret_cast<const short8v*>(&Bs[rb + m * 512]);
    }
    #pragma unroll
    for (int m = 0; m < 4; ++m)
      #pragma unroll
      for (int n = 0; n < 4; ++n)
        acc[m][n] = __builtin_amdgcn_mfma_f32_16x16x32_bf16(a[m], b[n], acc[m][n], 0, 0, 0);
    __syncthreads();
  }
  int ro = (lane >> 4) << 2, co = lane & 15;
  #pragma unroll
  for (int m = 0; m < 4; ++m) {
    #pragma unroll
    for (int j = 0; j < 4; ++j) {
      long long r = bm + wr + m * 16 + ro + j;
      long long base = (r / c_rpb) * c_bstride + (long long)((int)(r % c_rpb) + c_row0) * ldf;
      #pragma unroll
      for (int n = 0; n < 4; ++n) {
        long long c = bn + wc + n * 16 + co;
        float v = acc[m][n][j];
        if (bias) v += bias[c];
        if (act) v = 0.5f * v * (1.f + erff(v * 0.70710678118654752f));
        if (resid) v += resid[base + c];
        if (c < colsplit) Cf[base + c] = v;
        else Cb[r * ldb + (c - colsplit)] = f2bfu(v);
      }
    }
  }
}

// ======== MFMA flash attention (value path) — round-8 exact =================
template<int NKV, int NW, int PROBS, int KF32>
__global__ __launch_bounds__(NW * 64) void attn_mfma(
    const unsigned short* __restrict__ q, int q_rs, int q_bs, int q_off,
    const void* __restrict__ kv, int k_rs,
    const unsigned short* __restrict__ v, int v_rs,
    unsigned short* __restrict__ xab, int xa_rs, int xa_bs, int xa_off,
    float* __restrict__ probs, int NQtot)
{
  constexpr int KST = 68;
  constexpr int VST = NKV + 4;
  constexpr int NT_K = NKV / 16;
  constexpr int NTH = NW * 64;
  __shared__ unsigned short ksh[NKV * KST];
  __shared__ unsigned short qsh[NW * 16 * KST];
  __shared__ unsigned short vsh[64 * VST];
  __shared__ float ldsT[PROBS ? NW * 16 * 17 : 1];
  int bh = blockIdx.x, b = bh / HH, h = bh % HH;
  int rb = blockIdx.y * (NW * 16);
  int t = threadIdx.x;
  const float* kf = (const float*)kv;
  const unsigned short* ku = (const unsigned short*)kv;
  for (int i = t; i < NKV * 64; i += NTH) {
    int kr = i >> 6, d = i & 63;
    long long gi = (long long)(b * NKV + kr);
    ksh[kr * KST + d] = KF32 ? f2bfu(kf[gi * k_rs + h * DHD + d])
                             : ku[gi * k_rs + h * DHD + d];
    int kp = (kr & ~31) | (((kr >> 2) & 3) << 3) | (((kr >> 4) & 1) << 2) | (kr & 3);
    vsh[d * VST + kp] = v[gi * v_rs + h * DHD + d];
  }
  for (int i = t; i < NW * 16 * 64; i += NTH) {
    int qr = i >> 6, d = i & 63;
    int qg = rb + qr;
    qsh[qr * KST + d] = (qg < NQtot)
      ? q[(long long)(b * q_bs + q_off + qg) * q_rs + h * DHD + d] : (unsigned short)0;
  }
  __syncthreads();
  int wid = t >> 6, lane = t & 63;
  int l15 = lane & 15, lg = lane >> 4;
  short8v bq[2];
  #pragma unroll
  for (int ks = 0; ks < 2; ++ks)
    bq[ks] = *reinterpret_cast<const short8v*>(&qsh[(wid * 16 + l15) * KST + ks * 32 + lg * 8]);
  f32x4 s[NT_K];
  #pragma unroll
  for (int mt = 0; mt < NT_K; ++mt) s[mt] = (f32x4){0.f, 0.f, 0.f, 0.f};
  #pragma unroll
  for (int mt = 0; mt < NT_K; ++mt)
    #pragma unroll
    for (int ks = 0; ks < 2; ++ks) {
      short8v ka = *reinterpret_cast<const short8v*>(&ksh[(mt * 16 + l15) * KST + ks * 32 + lg * 8]);
      s[mt] = __builtin_amdgcn_mfma_f32_16x16x32_bf16(ka, bq[ks], s[mt], 0, 0, 0);
    }
  float m = -3.4e38f;
  #pragma unroll
  for (int mt = 0; mt < NT_K; ++mt)
    #pragma unroll
    for (int j = 0; j < 4; ++j) { s[mt][j] *= 0.125f; m = fmaxf(m, s[mt][j]); }
  m = fmaxf(m, __shfl_xor(m, 16)); m = fmaxf(m, __shfl_xor(m, 32));
  float ss = 0.f;
  #pragma unroll
  for (int mt = 0; mt < NT_K; ++mt)
    #pragma unroll
    for (int j = 0; j < 4; ++j) { s[mt][j] = __expf(s[mt][j] - m); ss += s[mt][j]; }
  ss += __shfl_xor(ss, 16); ss += __shfl_xor(ss, 32);
  float inv = 1.f / ss;
  #pragma unroll
  for (int mt = 0; mt < NT_K; ++mt)
    #pragma unroll
    for (int j = 0; j < 4; ++j) s[mt][j] *= inv;
  if (PROBS) {
    float* lT = &ldsT[wid * 16 * 17];
    #pragma unroll
    for (int mt = 0; mt < NT_K; ++mt) {
      #pragma unroll
      for (int j = 0; j < 4; ++j) lT[l15 * 17 + lg * 4 + j] = s[mt][j];
      #pragma unroll
      for (int m4 = 0; m4 < 4; ++m4) {
        int qg = rb + wid * 16 + m4 * 4 + lg;
        if (qg < NQtot)
          probs[((long long)(bh * q_bs + q_off + qg)) * NKV + mt * 16 + l15] =
              lT[(m4 * 4 + lg) * 17 + l15];
      }
    }
  }
  f32x4 o[4];
  #pragma unroll
  for (int nt = 0; nt < 4; ++nt) o[nt] = (f32x4){0.f, 0.f, 0.f, 0.f};
  #pragma unroll
  for (int c = 0; c < NKV / 32; ++c) {
    short8v a8;
    #pragma unroll
    for (int j = 0; j < 4; ++j) {
      a8[j]     = (short)f2bfu(s[2 * c][j]);
      a8[4 + j] = (short)f2bfu(s[2 * c + 1][j]);
    }
    #pragma unroll
    for (int nt = 0; nt < 4; ++nt) {
      short8v bv = *reinterpret_cast<const short8v*>(&vsh[(nt * 16 + l15) * VST + c * 32 + lg * 8]);
      o[nt] = __builtin_amdgcn_mfma_f32_16x16x32_bf16(a8, bv, o[nt], 0, 0, 0);
    }
  }
  #pragma unroll
  for (int nt = 0; nt < 4; ++nt)
    #pragma unroll
    for (int j = 0; j < 4; ++j) {
      int qg = rb + wid * 16 + lg * 4 + j;
      if (qg < NQtot)
        xab[(long long)(b * xa_bs + xa_off + qg) * xa_rs + h * DHD + nt * 16 + l15] =
            f2bfu(o[nt][j]);
    }
}

// ---- f32 attention for template rows (q<64): r10/r11-exact (known-good) ----
__global__ __launch_bounds__(1024) void attn_tmpl(
    const float* __restrict__ qt, const float* __restrict__ kf,
    const unsigned short* __restrict__ vb,
    unsigned short* __restrict__ xab, float* __restrict__ probs,
    float* __restrict__ atp)
{
  constexpr int VST = NN + 4;
  __shared__ float ksh[NN * 65];
  __shared__ unsigned short vsh[64 * VST];
  __shared__ float pss[16][NN];
  __shared__ float qsh[16][64];
  int bh = blockIdx.x, b = bh / HH, h = bh % HH;
  int t = threadIdx.x;
  for (int i = t; i < NN * 64; i += 1024) {
    int rr = i >> 6, d = i & 63;
    long long gi = (long long)(b * NN + rr);
    ksh[rr * 65 + d] = kf[gi * 768 + h * DHD + d];
    vsh[d * VST + rr] = vb[gi * 1536 + h * DHD + d];
  }
  __syncthreads();
  int wid = t >> 6, lane = t & 63;
  float at[4] = {};
  for (int q = wid; q < NT; q += 16) {
    qsh[wid][lane] = qt[(long long)(b * NT + q) * 768 + h * DHD + lane];
    float s[5];
    #pragma unroll
    for (int r = 0; r < 5; ++r) s[r] = 0.f;
    const float* kp = ksh + lane * 65;
    #pragma unroll 16
    for (int d = 0; d < 64; ++d) {
      float qd = qsh[wid][d];
      #pragma unroll
      for (int r = 0; r < 5; ++r)
        s[r] = fmaf(qd, kp[(r << 6) * 65 + d], s[r]);
    }
    float m = -3.4e38f;
    #pragma unroll
    for (int r = 0; r < 5; ++r) { s[r] *= 0.125f; m = fmaxf(m, s[r]); }
    #pragma unroll
    for (int off = 32; off > 0; off >>= 1) m = fmaxf(m, __shfl_xor(m, off));
    float ss = 0.f;
    #pragma unroll
    for (int r = 0; r < 5; ++r) { s[r] = __expf(s[r] - m); ss += s[r]; }
    #pragma unroll
    for (int off = 32; off > 0; off >>= 1) ss += __shfl_xor(ss, off);
    float inv = 1.f / ss;
    long long pb = ((long long)(bh * NN) + q) * NN;
    #pragma unroll
    for (int r = 0; r < 5; ++r) {
      float p = s[r] * inv;
      s[r] = p;
      pss[wid][lane + (r << 6)] = p;
      probs[pb + lane + (r << 6)] = p;
    }
    #pragma unroll
    for (int r = 1; r < 5; ++r) at[r - 1] += s[r];
    float acc = 0.f;
    const unsigned short* vp = vsh + lane * VST;
    #pragma unroll 8
    for (int j = 0; j < NN; j += 4) {
      float4 p4 = *reinterpret_cast<const float4*>(&pss[wid][j]);
      ushort4 v4 = *reinterpret_cast<const ushort4*>(&vp[j]);
      acc = fmaf(p4.x, bf2f(v4.x), acc);
      acc = fmaf(p4.y, bf2f(v4.y), acc);
      acc = fmaf(p4.z, bf2f(v4.z), acc);
      acc = fmaf(p4.w, bf2f(v4.w), acc);
    }
    xab[(long long)(b * NN + q) * 768 + h * DHD + lane] = f2bfu(acc);
  }
  #pragma unroll
  for (int r = 1; r < 5; ++r) pss[wid][lane + ((r - 1) << 6)] = at[r - 1];
  __syncthreads();
  if (t < 256) {
    float v = 0.f;
    #pragma unroll
    for (int w = 0; w < 16; ++w) v += pss[w][t];
    atp[(long long)bh * 256 + t] = v;
  }
}

// ---- Per-batch argsort(-attn_t), stable; emit keep/removed -----------------
__global__ __launch_bounds__(256) void sort_kernel(
    const float* __restrict__ atp, const int* __restrict__ gis,
    float* __restrict__ keep_out, float* __restrict__ rem_out,
    int* __restrict__ topk)
{
  int b = blockIdx.x, t = threadIdx.x;
  __shared__ float sv[256];
  __shared__ int   si[256];
  float v = 0.f;
  for (int h = 0; h < HH; ++h) v += atp[((long long)(b * HH + h) << 8) + t];
  sv[t] = v; si[t] = t;
  __syncthreads();
  for (int k = 2; k <= 256; k <<= 1) {
    for (int j = k >> 1; j > 0; j >>= 1) {
      int ixj = t ^ j;
      if (ixj > t) {
        float va = sv[t], vb2 = sv[ixj];
        int ia = si[t], ib = si[ixj];
        bool after = (va < vb2) || (va == vb2 && ia > ib);
        bool dirUp = ((t & k) == 0);
        if (after == dirUp) { sv[t] = vb2; sv[ixj] = va; si[t] = ib; si[ixj] = ia; }
      }
      __syncthreads();
    }
  }
  int o = si[t];
  if (t < LK) {
    topk[b * LK + t] = o;
    keep_out[b * LK + t] = (float)gis[(b << 8) + o];
  } else {
    rem_out[b * NREM + (t - LK)] = (float)gis[(b << 8) + o];
  }
}

__global__ __launch_bounds__(256) void gather_kernel(
    const float* __restrict__ x1, const int* __restrict__ topk, float* __restrict__ x2)
{
  int r = blockIdx.x, t = threadIdx.x;
  int b = r / 244, rr = r % 244;
  int src = (rr < NT) ? rr : (NT + topk[b * LK + (rr - NT)]);
  const float* s = x1 + (long long)(b * NN + src) * DD;
  float* d = x2 + (long long)r * DD;
  d[t] = s[t]; d[256 + t] = s[256 + t]; d[512 + t] = s[512 + t];
}

__global__ void git_kernel(const int* __restrict__ git, float* __restrict__ o)
{
  int i = blockIdx.x * 256 + threadIdx.x;
  if (i < BB * NT) o[i] = (float)git[i];
}

extern "C" void kernel_launch(void* const* d_in, const int* in_sizes, int n_in,
                              void* d_out, int out_size, void* d_ws, size_t ws_size,
                              hipStream_t stream) {
  (void)in_sizes; (void)n_in; (void)out_size; (void)ws_size;
  const float* x    = (const float*)d_in[0];
  const float* ps   = (const float*)d_in[1];
  const int*   git  = (const int*)d_in[2];
  const int*   gis  = (const int*)d_in[3];
  const float* g1   = (const float*)d_in[4];
  const float* b1   = (const float*)d_in[5];
  const float* Wqkv = (const float*)d_in[6];
  const float* Wproj= (const float*)d_in[7];
  const float* bproj= (const float*)d_in[8];
  const float* gt   = (const float*)d_in[9];
  const float* bt   = (const float*)d_in[10];
  const float* Wq   = (const float*)d_in[11];
  const float* Wk   = (const float*)d_in[12];
  const float* Wv   = (const float*)d_in[13];
  const float* Wtp  = (const float*)d_in[14];
  const float* btp  = (const float*)d_in[15];
  const float* g2   = (const float*)d_in[16];
  const float* b2   = (const float*)d_in[17];
  const float* W1   = (const float*)d_in[18];
  const float* b1m  = (const float*)d_in[19];
  const float* W2   = (const float*)d_in[20];
  const float* b2m  = (const float*)d_in[21];
  float* wsf = (float*)d_ws;
  float* out = (float*)d_out;
  unsigned short* WQVT = (unsigned short*)(wsf + OFF_WQVT);
  unsigned short* HBp  = (unsigned short*)(wsf + OFF_HB);
  unsigned short* QVp  = (unsigned short*)(wsf + OFF_QV);
  unsigned short* XAp  = (unsigned short*)(wsf + OFF_XA);
  unsigned short* WSMp = (unsigned short*)(wsf + OFF_WSM);
  unsigned short* WTS2 = (unsigned short*)(wsf + OFF_WTS2);
  unsigned short* SNp  = (unsigned short*)(wsf + OFF_SN);
  unsigned short* PSBp = (unsigned short*)(wsf + OFF_PSB);
  unsigned short* QT2p = (unsigned short*)(wsf + OFF_QT2);
  unsigned short* KTp  = (unsigned short*)(wsf + OFF_KT);
  unsigned short* VTp  = (unsigned short*)(wsf + OFF_VT);
  unsigned short* SAp  = (unsigned short*)(wsf + OFF_SA);
  unsigned short* H2p  = (unsigned short*)(wsf + OFF_H2);
  unsigned short* MIDp = (unsigned short*)(wsf + OFF_MIDB);
  #define WSLOT(i) (WSMp + (long long)(i) * 768 * 768)

  // S0a: Wqkv q-part and v-part -> 2 transposed bf16 planes
  hipLaunchKernelGGL(cvt_wt, dim3(24, 24, 2), dim3(256), 0, stream,
                     Wqkv, WQVT, DD, 3 * DD, 0, 1536, (long long)768 * 768);
  // S0b: 5 small weights -> transposed planes
  hipLaunchKernelGGL(cvt_w5, dim3(24, 24, 5), dim3(256), 0, stream,
                     Wproj, Wq, Wk, Wv, Wtp, WSMp);
  // S1: h = LN(x) -> f32 HF + bf16 HB
  hipLaunchKernelGGL((ln_kernel<3>), dim3(BB * NN), dim3(256), 0, stream,
                     x, wsf + OFF_HF, HBp, g1, b1, BB * NN, 0LL, 0);
  // S2a: k = h @ Wqkv[:,768:1536]  (f32, exact)
  hipLaunchKernelGGL(gemm_k, dim3(6, 80), dim3(512), 0, stream,
                     wsf + OFF_HF, BB * NN, 0LL, Wqkv + 768, 3 * DD,
                     wsf + OFF_KF, DD, BB * NN, DD);
  // S2b: q_template = h[template rows] @ Wqkv[:,0:768]
  hipLaunchKernelGGL(gemm_k, dim3(6, 16), dim3(512), 0, stream,
                     wsf + OFF_HF, NT, (long long)NN * DD, Wqkv, 3 * DD,
                     wsf + OFF_QTF, DD, BB * NT, DD);
  // S2c: [q|v] = h(bf16) @ [Wq-part|Wv-part]  (MFMA v2)
  hipLaunchKernelGGL(gemm_mfma, dim3(12, 80), dim3(256), 0, stream,
                     HBp, WQVT, (const float*)nullptr, (const float*)nullptr,
                     (float*)nullptr, 1, QVp, 1536, 0,
                     BB * NN, 1536, DD, BB * NN, 0LL, 0, 0);
  // S3B: MFMA attention rows 64..319 -> probs, xa
  hipLaunchKernelGGL((attn_mfma<NN, 8, 1, 1>), dim3(BB * HH, 2), dim3(512), 0, stream,
                     QVp, 1536, NN, NT,
                     (const void*)(wsf + OFF_KF), DD,
                     QVp + 768, 1536,
                     XAp, DD, NN, NT,
                     out + O_ATTN, 256);
  // S3A: f32 attention rows <64 -> probs, xa, attn_t
  hipLaunchKernelGGL(attn_tmpl, dim3(BB * HH), dim3(1024), 0, stream,
                     wsf + OFF_QTF, wsf + OFF_KF, QVp + 768,
                     XAp, out + O_ATTN, wsf + OFF_ATP);
  // S4: x1 = x + xa @ Wproj + bproj
  hipLaunchKernelGGL(gemm_mfma, dim3(6, 80), dim3(256), 0, stream,
                     XAp, WSLOT(0), bproj, x,
                     wsf + OFF_X1, DD, (unsigned short*)nullptr, 1, DD,
                     BB * NN, DD, DD, BB * NN, 0LL, 0, 0);
  // S5/S6/S7
  hipLaunchKernelGGL(sort_kernel, dim3(BB), dim3(256), 0, stream,
                     wsf + OFF_ATP, gis, out + O_KEEP, out + O_REM,
                     (int*)(wsf + OFF_TOPK));
  hipLaunchKernelGGL(git_kernel, dim3((BB * NT + 255) / 256), dim3(256), 0, stream,
                     git, out + O_GIT);
  hipLaunchKernelGGL(gather_kernel, dim3(BB * 244), dim3(256), 0, stream,
                     wsf + OFF_X1, (const int*)(wsf + OFF_TOPK), wsf + OFF_X2);
  // S7.5: ps -> bf16 (QV region dead)
  hipLaunchKernelGGL(cvt_bf_kernel, dim3(6144), dim3(256), 0, stream,
                     ps, PSBp, (long long)BB * NPS * DD);
  // S8: sn = LN(s) -> bf16
  hipLaunchKernelGGL((ln_kernel<1>), dim3(BB * LK), dim3(256), 0, stream,
                     wsf + OFF_X2, (float*)nullptr, SNp, gt, bt, LK, (long long)244 * DD, NT);
  // S9: qT = sn @ Wq -> bf16
  hipLaunchKernelGGL(gemm_mfma, dim3(6, 45), dim3(256), 0, stream,
                     SNp, WSLOT(1), (const float*)nullptr, (const float*)nullptr,
                     (float*)nullptr, 1, QT2p, DD, 0,
                     BB * LK, DD, DD, BB * LK, 0LL, 0, 0);
  // S10: kT = ps @ Wk -> bf16
  hipLaunchKernelGGL(gemm_mfma, dim3(6, 64), dim3(256), 0, stream,
                     PSBp, WSLOT(2), (const float*)nullptr, (const float*)nullptr,
                     (float*)nullptr, 1, KTp, DD, 0,
                     BB * NPS, DD, DD, BB * NPS, 0LL, 0, 0);
  // S11: vT = ps @ Wv -> bf16
  hipLaunchKernelGGL(gemm_mfma, dim3(6, 64), dim3(256), 0, stream,
                     PSBp, WSLOT(3), (const float*)nullptr, (const float*)nullptr,
                     (float*)nullptr, 1, VTp, DD, 0,
                     BB * NPS, DD, DD, BB * NPS, 0LL, 0, 0);
  // S12: stage-2 attention (MFMA) -> sa bf16
  hipLaunchKernelGGL((attn_mfma<NPS, 8, 0, 0>), dim3(BB * HH, 2), dim3(512), 0, stream,
                     QT2p, DD, LK, 0,
                     (const void*)KTp, DD,
                     VTp, DD,
                     SAp, DD, LK, 0,
                     (float*)nullptr, LK);
  // S13: s2 = s + sa @ Wtp + btp (into x2 rows 64..243)
  hipLaunchKernelGGL(gemm_mfma, dim3(6, 45), dim3(256), 0, stream,
                     SAp, WSLOT(4), btp, wsf + OFF_X2,
                     wsf + OFF_X2, DD, (unsigned short*)nullptr, 1, DD,
                     BB * LK, DD, DD, LK, (long long)244 * DD, NT, 0);
  // S14: h2 = LN(x2) -> bf16
  hipLaunchKernelGGL((ln_kernel<1>), dim3(BB * 244), dim3(256), 0, stream,
                     wsf + OFF_X2, (float*)nullptr, H2p, g2, b2, BB * 244, 0LL, 0);
  // S15: mid = gelu(h2 @ W1 + b1m) -> bf16
  hipLaunchKernelGGL(cvt_wt, dim3(96, 24, 1), dim3(256), 0, stream,
                     W1, WTS2, DD, 4 * DD, 0, 0, 0LL);
  hipLaunchKernelGGL(gemm_mfma, dim3(24, 61), dim3(256), 0, stream,
                     H2p, WTS2, b1m, (const float*)nullptr,
                     (float*)nullptr, 1, MIDp, 4 * DD, 0,
                     BB * 244, 4 * DD, DD, BB * 244, 0LL, 0, 1);
  // S16: x_out = x2 + mid @ W2 + b2m -> f32 d_out
  hipLaunchKernelGGL(cvt_wt, dim3(24, 96, 1), dim3(256), 0, stream,
                     W2, WTS2, 4 * DD, DD, 0, 0, 0LL);
  hipLaunchKernelGGL(gemm_mfma, dim3(6, 61), dim3(256), 0, stream,
                     MIDp, WTS2, b2m, wsf + OFF_X2,
                     out + O_X, DD, (unsigned short*)nullptr, 1, DD,
                     BB * 244, DD, 4 * DD, BB * 244, 0LL, 0, 0);
}